// Round 4
// baseline (890.744 us; speedup 1.0000x reference)
//
#include <hip/hip_runtime.h>
#include <cmath>

#define NPROP 384
#define NB 2
#define NCLS 11
#define NFG 10
#define BC_TOTAL (NB*NFG)          // 20
#define M_TOTAL (NB*NPROP)         // 768
#define FLAT_PER_IMG (NFG*NPROP)   // 3840
#define DET 100

// ws layout (in 4-byte words) — total 222752 words = 891 KB (proven footprint)
#define OFF_BOXES 0                // [BC][N][5]  38400
#define OFF_CORN  38400            // [BC][N][8]  61440  (x0..x3, y0..y3)
#define OFF_AREA  99840            // [BC][N]     7680
#define OFF_SCORE 107520           // [BC][N]     7680
#define OFF_VIDX  115200           // [BC][N]     7680  heavy: compacted valid idx; later: kept flat idx [NB][FLAT]
#define OFF_SUP   122880           // [BC][N][12] 92160 (u32 suppress bitrows)
#define OFF_MS    215040           // [B][FLAT]   7680  kept scores (compacted)
#define OFF_VCNT  222720           // [0..19] per-bc valid counts; [24..25] per-image kept counts

__device__ float inter_area_net(const float ax[4], const float ay[4],
                                const float bx[4], const float by[4]) {
    float d1x[4], d1y[4], d2x[4], d2y[4];
#pragma unroll
    for (int k = 0; k < 4; ++k) {
        int k1 = (k + 1) & 3;
        d1x[k] = ax[k1] - ax[k]; d1y[k] = ay[k1] - ay[k];
        d2x[k] = bx[k1] - bx[k]; d2y[k] = by[k1] - by[k];
    }
    float ex[32], ey[32];
    bool msk[24];
#pragma unroll
    for (int i = 0; i < 4; ++i) {
#pragma unroll
        for (int j = 0; j < 4; ++j) {
            float den = d1x[i]*d2y[j] - d1y[i]*d2x[j];
            float dfx = bx[j]-ax[i], dfy = by[j]-ay[i];
            float dens = (fabsf(den) < 1e-8f) ? 1.0f : den;
            float t = (dfx*d2y[j] - dfy*d2x[j]) / dens;
            float u = (dfx*d1y[i] - dfy*d1x[i]) / dens;
            bool ok = (fabsf(den) >= 1e-8f) && t >= 0.0f && t <= 1.0f
                                            && u >= 0.0f && u <= 1.0f;
            ex[i*4+j] = ax[i] + t*d1x[i];
            ey[i*4+j] = ay[i] + t*d1y[i];
            msk[i*4+j] = ok;
        }
    }
#pragma unroll
    for (int i = 0; i < 4; ++i) {   // corners of A inside B
        bool allp = true, alln = true;
#pragma unroll
        for (int j = 0; j < 4; ++j) {
            float cr = d2x[j]*(ay[i]-by[j]) - d2y[j]*(ax[i]-bx[j]);
            allp = allp && (cr >= -1e-6f);
            alln = alln && (cr <= 1e-6f);
        }
        ex[16+i] = ax[i]; ey[16+i] = ay[i]; msk[16+i] = allp || alln;
    }
#pragma unroll
    for (int i = 0; i < 4; ++i) {   // corners of B inside A
        bool allp = true, alln = true;
#pragma unroll
        for (int j = 0; j < 4; ++j) {
            float cr = d1x[j]*(by[i]-ay[j]) - d1y[j]*(bx[i]-ax[j]);
            allp = allp && (cr >= -1e-6f);
            alln = alln && (cr <= 1e-6f);
        }
        ex[20+i] = bx[i]; ey[20+i] = by[i]; msk[20+i] = allp || alln;
    }
    int nv = 0; float sx = 0.f, sy = 0.f;
#pragma unroll
    for (int k = 0; k < 24; ++k)
        if (msk[k]) { nv++; sx += ex[k]; sy += ey[k]; }
    float fm = (float)(nv > 1 ? nv : 1);
    float cx = sx / fm, cy = sy / fm;
    unsigned key[32];
#pragma unroll
    for (int k = 0; k < 24; ++k) {
        float qx = msk[k] ? ex[k] : cx;
        float qy = msk[k] ? ey[k] : cy;
        ex[k] = qx; ey[k] = qy;
        float dx = qx - cx, dy = qy - cy;        // parked: dx=dy=+0
        float den = fabsf(dx) + fabsf(dy);
        float r = (den > 0.0f) ? dy / den : 0.0f;
        float p = (dx >= 0.0f) ? r : ((dy >= 0.0f) ? 2.0f - r : -2.0f - r);
        p = p + 0.0f;                             // canonicalize -0 -> +0
        unsigned u = __float_as_uint(p);
        u = (u & 0x80000000u) ? ~u : (u | 0x80000000u);
        key[k] = (u & 0xFFFFFFE0u) | (unsigned)k;
    }
#pragma unroll
    for (int k = 24; k < 32; ++k) { key[k] = 0xFFFFFFFFu; ex[k] = 0.f; ey[k] = 0.f; }
    // bitonic sort, 32 elements ascending, fully unrolled (static idx -> VGPRs)
#pragma unroll
    for (int k = 2; k <= 32; k <<= 1) {
#pragma unroll
        for (int j = k >> 1; j > 0; j >>= 1) {
#pragma unroll
            for (int i = 0; i < 32; ++i) {
                int l = i ^ j;
                if (l > i) {
                    bool up = ((i & k) == 0);
                    unsigned ka = key[i], kb = key[l];
                    bool sw = up ? (ka > kb) : (ka < kb);
                    float xa = ex[i], xb = ex[l];
                    float ya = ey[i], yb = ey[l];
                    key[i] = sw ? kb : ka; key[l] = sw ? ka : kb;
                    ex[i]  = sw ? xb : xa; ex[l]  = sw ? xa : xb;
                    ey[i]  = sw ? yb : ya; ey[l]  = sw ? ya : yb;
                }
            }
        }
    }
    float s = 0.f;
#pragma unroll
    for (int k = 0; k < 24; ++k) {
        int n = (k + 1 == 24) ? 0 : (k + 1);
        s += ex[k]*ey[n] - ey[k]*ex[n];
    }
    float area = 0.5f * fabsf(s);
    return (nv >= 3) ? area : 0.0f;
}

__global__ __launch_bounds__(256)
void prep_kernel(const float* __restrict__ logits,
                 const float* __restrict__ boxreg,
                 const float* __restrict__ rrects,
                 float* __restrict__ ws,
                 float* __restrict__ out) {
    int m = blockIdx.x * blockDim.x + threadIdx.x;
    if (m >= M_TOTAL) return;
    out[m] = 0.0f;                               // zero 1400-float output
    if (m + M_TOTAL < NB*DET*6 + NB*DET) out[m + M_TOTAL] = 0.0f;
    int b = m / NPROP, n = m % NPROP;
    float lg[NCLS];
    float mx = -INFINITY;
#pragma unroll
    for (int c = 0; c < NCLS; ++c) { lg[c] = logits[m*NCLS+c]; mx = fmaxf(mx, lg[c]); }
    float exo[NCLS]; float sum = 0.f;
#pragma unroll
    for (int c = 0; c < NCLS; ++c) { exo[c] = expf(lg[c]-mx); sum += exo[c]; }
    float axc = rrects[m*5+0], ayc = rrects[m*5+1];
    float aw  = rrects[m*5+2], ah  = rrects[m*5+3], aa = rrects[m*5+4];
    float* boxes = ws + OFF_BOXES;
    float* corn  = ws + OFF_CORN;
    float* areaA = ws + OFF_AREA;
    float* scoreA= ws + OFF_SCORE;
    for (int cls = 1; cls < NCLS; ++cls) {
        int o = ((b*NFG + (cls-1))*NPROP + n);
        float prob = exo[cls] / sum;
        const float* rel = boxreg + m*(NCLS*5) + cls*5;
        float dx = rel[0] / 10.0f;
        float dy = rel[1] / 10.0f;
        float dw = fminf(rel[2] / 5.0f, 4.1351665567423205f);
        float dh = fminf(rel[3] / 5.0f, 4.1351665567423205f);
        float da = rel[4];
        float px = dx*aw + axc;
        float py = dy*ah + ayc;
        float pw = expf(dw)*aw;
        float ph = expf(dh)*ah;
        float pa = da*57.29577951308232f + aa;
        float xm = pa + 180.0f;
        float r = fmodf(xm, 360.0f);
        if (r < 0.0f) r += 360.0f;
        pa = r - 180.0f;
        boxes[o*5+0]=px; boxes[o*5+1]=py; boxes[o*5+2]=pw; boxes[o*5+3]=ph; boxes[o*5+4]=pa;
        float t = pa * 0.017453292519943295f;
        float ct = cosf(t), st = sinf(t);
        float hx = pw*0.5f, hy = ph*0.5f;
        float lx[4] = {-hx, hx, hx, -hx};
        float ly[4] = {-hy, -hy, hy, hy};
#pragma unroll
        for (int k = 0; k < 4; ++k) {
            corn[o*8+k]   = px + lx[k]*ct - ly[k]*st;
            corn[o*8+4+k] = py + lx[k]*st + ly[k]*ct;
        }
        areaA[o]  = pw*ph;
        scoreA[o] = prob;
    }
}

// zero suppress bitrows + kept counters + compact valid indices per (b,cls)
__global__ __launch_bounds__(384)
void compact_kernel(float* __restrict__ ws) {
    __shared__ int cntS;
    int bc = blockIdx.x, t = threadIdx.x;
    unsigned int* supw = (unsigned int*)(ws + OFF_SUP);
    unsigned int* vidx = (unsigned int*)(ws + OFF_VIDX);
    unsigned int* vcnt = (unsigned int*)(ws + OFF_VCNT);
    int r0 = (bc*NPROP + t)*12;
#pragma unroll
    for (int w = 0; w < 12; ++w) supw[r0 + w] = 0u;
    if (t == 0) cntS = 0;
    if (bc == 0 && t < NB) vcnt[24 + t] = 0u;    // kept-list counters
    __syncthreads();
    float sc = ws[OFF_SCORE + bc*NPROP + t];
    if (sc > 0.05f) {
        int p = atomicAdd(&cntS, 1);
        vidx[bc*NPROP + p] = (unsigned)t;
    }
    __syncthreads();
    if (t == 0) vcnt[bc] = (unsigned)cntS;
}

// one wave per (bc, a, 64-chunk of b) over COMPACTED valid indices
__global__ __launch_bounds__(256)
void heavy_kernel(float* __restrict__ ws) {
    const float* boxes = ws + OFF_BOXES;
    const float* corn  = ws + OFF_CORN;
    const float* areaA = ws + OFF_AREA;
    const unsigned int* vidx = (const unsigned int*)(ws + OFF_VIDX);
    const unsigned int* vcnt = (const unsigned int*)(ws + OFF_VCNT);
    unsigned int* supw = (unsigned int*)(ws + OFF_SUP);
    int wave = (blockIdx.x * blockDim.x + threadIdx.x) >> 6;
    int lane = threadIdx.x & 63;
    int bw = wave % 6;
    int a  = (wave / 6) % NPROP;
    int bc = wave / (6 * NPROP);
    if (bc >= BC_TOTAL) return;
    int cnt = (int)vcnt[bc];
    if (a >= cnt || bw*64 >= cnt) return;        // wave-uniform exits
    int i = (int)vidx[bc*NPROP + a];
    int rowi = bc*NPROP + i;
    int b = bw*64 + lane;
    bool act = b < cnt;
    int j = act ? (int)vidx[bc*NPROP + b] : i;
    int rowj = bc*NPROP + j;
    bool go = act && (j != i);
    if (go) {
        float cxi = boxes[rowi*5+0], cyi = boxes[rowi*5+1];
        float wi  = boxes[rowi*5+2], hi  = boxes[rowi*5+3];
        float cxj = boxes[rowj*5+0], cyj = boxes[rowj*5+1];
        float wj  = boxes[rowj*5+2], hj  = boxes[rowj*5+3];
        float ddx = cxi-cxj, ddy = cyi-cyj;
        float rr = 0.5f*sqrtf(wi*wi+hi*hi) + 0.5f*sqrtf(wj*wj+hj*hj);
        go = (ddx*ddx + ddy*ddy <= rr*rr);
        if (go) {
            float A = areaA[rowi], Bv = areaA[rowj];
            float mn = fminf(A, Bv);
            go = (3.0f*mn > A + Bv);             // else iou <= 0.5 provably
        }
    }
    bool pred = false;
    if (go) {
        float axp[4], ayp[4], bxp[4], byp[4];
#pragma unroll
        for (int k = 0; k < 4; ++k) {
            axp[k] = corn[rowi*8+k]; ayp[k] = corn[rowi*8+4+k];
            bxp[k] = corn[rowj*8+k]; byp[k] = corn[rowj*8+4+k];
        }
        float inter = inter_area_net(axp, ayp, bxp, byp);
        float iou = inter / (areaA[rowi] + areaA[rowj] - inter + 1e-8f);
        pred = iou > 0.5f;
    }
    if (pred) atomicOr(&supw[rowi*12 + (j >> 5)], 1u << (j & 31));
}

__global__ __launch_bounds__(384)
void nms_kernel(float* __restrict__ ws) {
    __shared__ float scoreL[NPROP];
    __shared__ int orderL[NPROP];
    __shared__ unsigned int supL[NPROP*12];   // 18.4 KB
    __shared__ unsigned char keepS[NPROP];
    __shared__ int nvalidS;
    int bc = blockIdx.x;
    const float* scoreA = ws + OFF_SCORE;
    const unsigned int* supbG = (const unsigned int*)(ws + OFF_SUP);
    unsigned int* kidxG = (unsigned int*)(ws + OFF_VIDX);   // reused as kept flat idx [NB][FLAT]
    float* kscG = ws + OFF_MS;                              // kept scores [NB][FLAT]
    unsigned int* kcntG = (unsigned int*)(ws + OFF_VCNT) + 24;
    int t = threadIdx.x;
    if (t == 0) nvalidS = 0;
    scoreL[t] = scoreA[bc*NPROP+t];
    keepS[t] = 0;
    __syncthreads();
    {
        bool vi = scoreL[t] > 0.05f;
        float si = vi ? scoreL[t] : -INFINITY;
        int r = 0;
        for (int k = 0; k < NPROP; ++k) {
            bool vk = scoreL[k] > 0.05f;
            float sk = vk ? scoreL[k] : -INFINITY;
            r += (sk > si) || (sk == si && k < t);
        }
        orderL[r] = t;
        if (vi) atomicAdd(&nvalidS, 1);
    }
    for (int k = t; k < NPROP*12; k += NPROP) supL[k] = supbG[bc*NPROP*12 + k];
    __syncthreads();
    if (t == 0) {
        unsigned int sup[12];
#pragma unroll
        for (int w = 0; w < 12; ++w) sup[w] = 0u;
        int NV = nvalidS;
        for (int p = 0; p < NV; ++p) {      // valid entries sort first
            int o = orderL[p];
            if (!((sup[o>>5] >> (o & 31)) & 1u)) {
                keepS[o] = 1;
#pragma unroll
                for (int w = 0; w < 12; ++w) sup[w] |= supL[o*12 + w];
            }
        }
    }
    __syncthreads();
    // compact kept boxes into per-image list (rank formula is order-independent)
    if (keepS[t]) {
        int img = bc / NFG;
        int f = (bc % NFG) * NPROP + t;
        int pos = (int)atomicAdd(&kcntG[img], 1u);
        kidxG[img*FLAT_PER_IMG + pos] = (unsigned)f;
        kscG [img*FLAT_PER_IMG + pos] = scoreL[t];
    }
}

// one block per image: rank-count among the K kept candidates only (K << 3840)
__global__ __launch_bounds__(256)
void topk_kernel(const float* __restrict__ ws, float* __restrict__ out) {
    __shared__ float ssc[FLAT_PER_IMG];
    __shared__ int   sidx[FLAT_PER_IMG];
    int b = blockIdx.x, t = threadIdx.x;
    const unsigned int* kidxG = (const unsigned int*)(ws + OFF_VIDX);
    const float* kscG = ws + OFF_MS;
    const unsigned int* kcntG = (const unsigned int*)(ws + OFF_VCNT) + 24;
    const float* boxes = ws + OFF_BOXES;
    int K = (int)kcntG[b];
    for (int k = t; k < K; k += 256) {
        ssc[k]  = kscG[b*FLAT_PER_IMG + k];
        sidx[k] = (int)kidxG[b*FLAT_PER_IMG + k];
    }
    __syncthreads();
    for (int e = t; e < K; e += 256) {
        float s = ssc[e]; int f = sidx[e];
        int r = 0;
        for (int k = 0; k < K; ++k) {
            float sk = ssc[k]; int fk = sidx[k];
            r += (sk > s) || (sk == s && fk < f);
        }
        if (r < DET) {
            int src = b*FLAT_PER_IMG + f;
            float* row = out + (b*DET + r)*6;
#pragma unroll
            for (int q = 0; q < 5; ++q) row[q] = boxes[src*5+q];
            row[5] = s;
            out[NB*DET*6 + b*DET + r] = (float)(f / NPROP + 1);
        }
    }
}

extern "C" void kernel_launch(void* const* d_in, const int* in_sizes, int n_in,
                              void* d_out, int out_size, void* d_ws, size_t ws_size,
                              hipStream_t stream) {
    const float* logits = (const float*)d_in[0];
    const float* boxreg = (const float*)d_in[1];
    const float* rrects = (const float*)d_in[2];
    float* out = (float*)d_out;
    float* ws  = (float*)d_ws;
    (void)in_sizes; (void)n_in; (void)out_size; (void)ws_size;

    prep_kernel<<<(M_TOTAL + 255) / 256, 256, 0, stream>>>(logits, boxreg, rrects, ws, out);
    compact_kernel<<<BC_TOTAL, NPROP, 0, stream>>>(ws);
    heavy_kernel<<<(BC_TOTAL * NPROP * 6 * 64) / 256, 256, 0, stream>>>(ws);
    nms_kernel<<<BC_TOTAL, NPROP, 0, stream>>>(ws);
    topk_kernel<<<NB, 256, 0, stream>>>(ws, out);
}

// Round 5
// 202.614 us; speedup vs baseline: 4.3963x; 4.3963x over previous
//
#include <hip/hip_runtime.h>
#include <cmath>

#define NPROP 384
#define NB 2
#define NCLS 11
#define NFG 10
#define BC_TOTAL (NB*NFG)          // 20
#define M_TOTAL (NB*NPROP)         // 768
#define FLAT_PER_IMG (NFG*NPROP)   // 3840
#define DET 100

// ws layout (in 4-byte words) — total 222752 words = 891 KB (proven footprint)
#define OFF_BOXES 0                // [BC][N][5]  38400
#define OFF_CORN  38400            // [BC][N][8]  61440  (x0..x3, y0..y3)
#define OFF_AREA  99840            // [BC][N]     7680
#define OFF_SCORE 107520           // [BC][N]     7680
#define OFF_VIDX  115200           // [BC][N]     7680  heavy: compacted valid idx; later: kept flat idx [NB][FLAT]
#define OFF_SUP   122880           // [BC][N][12] 92160 (u32 suppress bitrows)
#define OFF_MS    215040           // [B][FLAT]   7680  kept scores (compacted)
#define OFF_VCNT  222720           // [0..19] per-bc valid counts; [24..25] per-image kept counts

__device__ float inter_area_net(const float ax[4], const float ay[4],
                                const float bx[4], const float by[4]) {
    float d1x[4], d1y[4], d2x[4], d2y[4];
#pragma unroll
    for (int k = 0; k < 4; ++k) {
        int k1 = (k + 1) & 3;
        d1x[k] = ax[k1] - ax[k]; d1y[k] = ay[k1] - ay[k];
        d2x[k] = bx[k1] - bx[k]; d2y[k] = by[k1] - by[k];
    }
    float ex[32], ey[32];
    bool msk[24];
#pragma unroll
    for (int i = 0; i < 4; ++i) {
#pragma unroll
        for (int j = 0; j < 4; ++j) {
            float den = d1x[i]*d2y[j] - d1y[i]*d2x[j];
            float dfx = bx[j]-ax[i], dfy = by[j]-ay[i];
            float dens = (fabsf(den) < 1e-8f) ? 1.0f : den;
            float t = (dfx*d2y[j] - dfy*d2x[j]) / dens;
            float u = (dfx*d1y[i] - dfy*d1x[i]) / dens;
            bool ok = (fabsf(den) >= 1e-8f) && t >= 0.0f && t <= 1.0f
                                            && u >= 0.0f && u <= 1.0f;
            ex[i*4+j] = ax[i] + t*d1x[i];
            ey[i*4+j] = ay[i] + t*d1y[i];
            msk[i*4+j] = ok;
        }
    }
#pragma unroll
    for (int i = 0; i < 4; ++i) {   // corners of A inside B
        bool allp = true, alln = true;
#pragma unroll
        for (int j = 0; j < 4; ++j) {
            float cr = d2x[j]*(ay[i]-by[j]) - d2y[j]*(ax[i]-bx[j]);
            allp = allp && (cr >= -1e-6f);
            alln = alln && (cr <= 1e-6f);
        }
        ex[16+i] = ax[i]; ey[16+i] = ay[i]; msk[16+i] = allp || alln;
    }
#pragma unroll
    for (int i = 0; i < 4; ++i) {   // corners of B inside A
        bool allp = true, alln = true;
#pragma unroll
        for (int j = 0; j < 4; ++j) {
            float cr = d1x[j]*(by[i]-ay[j]) - d1y[j]*(bx[i]-ax[j]);
            allp = allp && (cr >= -1e-6f);
            alln = alln && (cr <= 1e-6f);
        }
        ex[20+i] = bx[i]; ey[20+i] = by[i]; msk[20+i] = allp || alln;
    }
    int nv = 0; float sx = 0.f, sy = 0.f;
#pragma unroll
    for (int k = 0; k < 24; ++k)
        if (msk[k]) { nv++; sx += ex[k]; sy += ey[k]; }
    float fm = (float)(nv > 1 ? nv : 1);
    float cx = sx / fm, cy = sy / fm;
    unsigned key[32];
#pragma unroll
    for (int k = 0; k < 24; ++k) {
        float qx = msk[k] ? ex[k] : cx;
        float qy = msk[k] ? ey[k] : cy;
        ex[k] = qx; ey[k] = qy;
        float dx = qx - cx, dy = qy - cy;        // parked: dx=dy=+0
        float den = fabsf(dx) + fabsf(dy);
        float r = (den > 0.0f) ? dy / den : 0.0f;
        float p = (dx >= 0.0f) ? r : ((dy >= 0.0f) ? 2.0f - r : -2.0f - r);
        p = p + 0.0f;                             // canonicalize -0 -> +0
        unsigned u = __float_as_uint(p);
        u = (u & 0x80000000u) ? ~u : (u | 0x80000000u);
        key[k] = (u & 0xFFFFFFE0u) | (unsigned)k;
    }
#pragma unroll
    for (int k = 24; k < 32; ++k) { key[k] = 0xFFFFFFFFu; ex[k] = 0.f; ey[k] = 0.f; }
    // bitonic sort, 32 elements ascending, fully unrolled (static idx -> VGPRs)
#pragma unroll
    for (int k = 2; k <= 32; k <<= 1) {
#pragma unroll
        for (int j = k >> 1; j > 0; j >>= 1) {
#pragma unroll
            for (int i = 0; i < 32; ++i) {
                int l = i ^ j;
                if (l > i) {
                    bool up = ((i & k) == 0);
                    unsigned ka = key[i], kb = key[l];
                    bool sw = up ? (ka > kb) : (ka < kb);
                    float xa = ex[i], xb = ex[l];
                    float ya = ey[i], yb = ey[l];
                    key[i] = sw ? kb : ka; key[l] = sw ? ka : kb;
                    ex[i]  = sw ? xb : xa; ex[l]  = sw ? xa : xb;
                    ey[i]  = sw ? yb : ya; ey[l]  = sw ? ya : yb;
                }
            }
        }
    }
    float s = 0.f;
#pragma unroll
    for (int k = 0; k < 24; ++k) {
        int n = (k + 1 == 24) ? 0 : (k + 1);
        s += ex[k]*ey[n] - ey[k]*ex[n];
    }
    float area = 0.5f * fabsf(s);
    return (nv >= 3) ? area : 0.0f;
}

__global__ __launch_bounds__(256)
void prep_kernel(const float* __restrict__ logits,
                 const float* __restrict__ boxreg,
                 const float* __restrict__ rrects,
                 float* __restrict__ ws,
                 float* __restrict__ out) {
    int m = blockIdx.x * blockDim.x + threadIdx.x;
    if (m >= M_TOTAL) return;
    out[m] = 0.0f;                               // zero 1400-float output
    if (m + M_TOTAL < NB*DET*6 + NB*DET) out[m + M_TOTAL] = 0.0f;
    int b = m / NPROP, n = m % NPROP;
    float lg[NCLS];
    float mx = -INFINITY;
#pragma unroll
    for (int c = 0; c < NCLS; ++c) { lg[c] = logits[m*NCLS+c]; mx = fmaxf(mx, lg[c]); }
    float exo[NCLS]; float sum = 0.f;
#pragma unroll
    for (int c = 0; c < NCLS; ++c) { exo[c] = expf(lg[c]-mx); sum += exo[c]; }
    float axc = rrects[m*5+0], ayc = rrects[m*5+1];
    float aw  = rrects[m*5+2], ah  = rrects[m*5+3], aa = rrects[m*5+4];
    float* boxes = ws + OFF_BOXES;
    float* corn  = ws + OFF_CORN;
    float* areaA = ws + OFF_AREA;
    float* scoreA= ws + OFF_SCORE;
    for (int cls = 1; cls < NCLS; ++cls) {
        int o = ((b*NFG + (cls-1))*NPROP + n);
        float prob = exo[cls] / sum;
        const float* rel = boxreg + m*(NCLS*5) + cls*5;
        float dx = rel[0] / 10.0f;
        float dy = rel[1] / 10.0f;
        float dw = fminf(rel[2] / 5.0f, 4.1351665567423205f);
        float dh = fminf(rel[3] / 5.0f, 4.1351665567423205f);
        float da = rel[4];
        float px = dx*aw + axc;
        float py = dy*ah + ayc;
        float pw = expf(dw)*aw;
        float ph = expf(dh)*ah;
        float pa = da*57.29577951308232f + aa;
        float xm = pa + 180.0f;
        float r = fmodf(xm, 360.0f);
        if (r < 0.0f) r += 360.0f;
        pa = r - 180.0f;
        boxes[o*5+0]=px; boxes[o*5+1]=py; boxes[o*5+2]=pw; boxes[o*5+3]=ph; boxes[o*5+4]=pa;
        float t = pa * 0.017453292519943295f;
        float ct = cosf(t), st = sinf(t);
        float hx = pw*0.5f, hy = ph*0.5f;
        float lx[4] = {-hx, hx, hx, -hx};
        float ly[4] = {-hy, -hy, hy, hy};
#pragma unroll
        for (int k = 0; k < 4; ++k) {
            corn[o*8+k]   = px + lx[k]*ct - ly[k]*st;
            corn[o*8+4+k] = py + lx[k]*st + ly[k]*ct;
        }
        areaA[o]  = pw*ph;
        scoreA[o] = prob;
    }
}

// zero suppress bitrows + kept counters + compact valid indices per (b,cls)
__global__ __launch_bounds__(384)
void compact_kernel(float* __restrict__ ws) {
    __shared__ int cntS;
    int bc = blockIdx.x, t = threadIdx.x;
    unsigned int* supw = (unsigned int*)(ws + OFF_SUP);
    unsigned int* vidx = (unsigned int*)(ws + OFF_VIDX);
    unsigned int* vcnt = (unsigned int*)(ws + OFF_VCNT);
    int r0 = (bc*NPROP + t)*12;
#pragma unroll
    for (int w = 0; w < 12; ++w) supw[r0 + w] = 0u;
    if (t == 0) cntS = 0;
    if (bc == 0 && t < NB) vcnt[24 + t] = 0u;    // kept-list counters
    __syncthreads();
    float sc = ws[OFF_SCORE + bc*NPROP + t];
    if (sc > 0.05f) {
        int p = atomicAdd(&cntS, 1);
        vidx[bc*NPROP + p] = (unsigned)t;
    }
    __syncthreads();
    if (t == 0) vcnt[bc] = (unsigned)cntS;
}

// one wave per (bc, a, 64-chunk of b) over COMPACTED valid indices
__global__ __launch_bounds__(256)
void heavy_kernel(float* __restrict__ ws) {
    const float* boxes = ws + OFF_BOXES;
    const float* corn  = ws + OFF_CORN;
    const float* areaA = ws + OFF_AREA;
    const unsigned int* vidx = (const unsigned int*)(ws + OFF_VIDX);
    const unsigned int* vcnt = (const unsigned int*)(ws + OFF_VCNT);
    unsigned int* supw = (unsigned int*)(ws + OFF_SUP);
    int wave = (blockIdx.x * blockDim.x + threadIdx.x) >> 6;
    int lane = threadIdx.x & 63;
    int bw = wave % 6;
    int a  = (wave / 6) % NPROP;
    int bc = wave / (6 * NPROP);
    if (bc >= BC_TOTAL) return;
    int cnt = (int)vcnt[bc];
    if (a >= cnt || bw*64 >= cnt) return;        // wave-uniform exits
    int i = (int)vidx[bc*NPROP + a];
    int rowi = bc*NPROP + i;
    int b = bw*64 + lane;
    bool act = b < cnt;
    int j = act ? (int)vidx[bc*NPROP + b] : i;
    int rowj = bc*NPROP + j;
    bool go = act && (j != i);
    if (go) {
        float cxi = boxes[rowi*5+0], cyi = boxes[rowi*5+1];
        float wi  = boxes[rowi*5+2], hi  = boxes[rowi*5+3];
        float cxj = boxes[rowj*5+0], cyj = boxes[rowj*5+1];
        float wj  = boxes[rowj*5+2], hj  = boxes[rowj*5+3];
        float ddx = cxi-cxj, ddy = cyi-cyj;
        float rr = 0.5f*sqrtf(wi*wi+hi*hi) + 0.5f*sqrtf(wj*wj+hj*hj);
        go = (ddx*ddx + ddy*ddy <= rr*rr);
        if (go) {
            float A = areaA[rowi], Bv = areaA[rowj];
            float mn = fminf(A, Bv);
            go = (3.0f*mn > A + Bv);             // else iou <= 0.5 provably
        }
    }
    bool pred = false;
    if (go) {
        float axp[4], ayp[4], bxp[4], byp[4];
#pragma unroll
        for (int k = 0; k < 4; ++k) {
            axp[k] = corn[rowi*8+k]; ayp[k] = corn[rowi*8+4+k];
            bxp[k] = corn[rowj*8+k]; byp[k] = corn[rowj*8+4+k];
        }
        float inter = inter_area_net(axp, ayp, bxp, byp);
        float iou = inter / (areaA[rowi] + areaA[rowj] - inter + 1e-8f);
        pred = iou > 0.5f;
    }
    if (pred) atomicOr(&supw[rowi*12 + (j >> 5)], 1u << (j & 31));
}

__global__ __launch_bounds__(384)
void nms_kernel(float* __restrict__ ws) {
    __shared__ float scoreL[NPROP];
    __shared__ int orderL[NPROP];
    __shared__ unsigned int supL[NPROP*12];   // 18.4 KB
    __shared__ unsigned char keepS[NPROP];
    __shared__ int nvalidS;
    int bc = blockIdx.x;
    const float* scoreA = ws + OFF_SCORE;
    const unsigned int* supbG = (const unsigned int*)(ws + OFF_SUP);
    unsigned int* kidxG = (unsigned int*)(ws + OFF_VIDX);   // kept flat idx [NB][FLAT]
    float* kscG = ws + OFF_MS;                              // kept scores [NB][FLAT]
    unsigned int* kcntG = (unsigned int*)(ws + OFF_VCNT) + 24;
    int t = threadIdx.x;
    if (t == 0) nvalidS = 0;
    scoreL[t] = scoreA[bc*NPROP+t];
    keepS[t] = 0;
    __syncthreads();
    {
        bool vi = scoreL[t] > 0.05f;
        float si = vi ? scoreL[t] : -INFINITY;
        int r = 0;
        for (int k = 0; k < NPROP; ++k) {
            bool vk = scoreL[k] > 0.05f;
            float sk = vk ? scoreL[k] : -INFINITY;
            r += (sk > si) || (sk == si && k < t);
        }
        orderL[r] = t;
        if (vi) atomicAdd(&nvalidS, 1);
    }
    for (int k = t; k < NPROP*12; k += NPROP) supL[k] = supbG[bc*NPROP*12 + k];
    __syncthreads();
    if (t == 0) {
        unsigned int sup[12];
#pragma unroll
        for (int w = 0; w < 12; ++w) sup[w] = 0u;
        int NV = nvalidS;
        for (int p = 0; p < NV; ++p) {      // valid entries sort first
            int o = orderL[p];
            if (!((sup[o>>5] >> (o & 31)) & 1u)) {
                keepS[o] = 1;
#pragma unroll
                for (int w = 0; w < 12; ++w) sup[w] |= supL[o*12 + w];
            }
        }
    }
    __syncthreads();
    // compact kept boxes into per-image list (rank formula is order-independent)
    if (keepS[t]) {
        int img = bc / NFG;
        int f = (bc % NFG) * NPROP + t;
        int pos = (int)atomicAdd(&kcntG[img], 1u);
        kidxG[img*FLAT_PER_IMG + pos] = (unsigned)f;
        kscG [img*FLAT_PER_IMG + pos] = scoreL[t];
    }
}

// 16 blocks per image; whole kept list as u64 keys in LDS; each thread ranks
// one candidate with an unroll-16 independent-load loop (latency pipelined).
// key = (score_bits << 32) | (~f): key_k > key_e  <=>  beats in (score desc,
// f asc) order — exact lax.top_k tie semantics (scores > 0, f distinct).
__global__ __launch_bounds__(256)
void topk_kernel(const float* __restrict__ ws, float* __restrict__ out) {
    __shared__ unsigned long long keyL[FLAT_PER_IMG];
    int b = blockIdx.x >> 4;
    int slice = blockIdx.x & 15;
    int t = threadIdx.x;
    const unsigned int* kidxG = (const unsigned int*)(ws + OFF_VIDX);
    const float* kscG = ws + OFF_MS;
    const unsigned int* kcntG = (const unsigned int*)(ws + OFF_VCNT) + 24;
    const float* boxes = ws + OFF_BOXES;
    int K = (int)kcntG[b];
    int KP = (K + 15) & ~15;
    for (int k = t; k < KP; k += 256) {
        unsigned long long key = 0ull;
        if (k < K) {
            unsigned sb = __float_as_uint(kscG[b*FLAT_PER_IMG + k]);
            unsigned f  = kidxG[b*FLAT_PER_IMG + k];
            key = ((unsigned long long)sb << 32) | (unsigned long long)(0xFFFFFFFFu - f);
        }
        keyL[k] = key;
    }
    __syncthreads();
    int e = slice*256 + t;
    if (e >= K) return;
    unsigned long long my = keyL[e];
    int r = 0;
    for (int k = 0; k < KP; k += 16) {
        int acc = 0;
#pragma unroll
        for (int q = 0; q < 16; ++q)
            acc += (keyL[k+q] > my) ? 1 : 0;
        r += acc;
    }
    if (r < DET) {
        unsigned f = 0xFFFFFFFFu - (unsigned)(my & 0xFFFFFFFFu);
        float s = __uint_as_float((unsigned)(my >> 32));
        int src = b*FLAT_PER_IMG + (int)f;
        float* row = out + (b*DET + r)*6;
#pragma unroll
        for (int q = 0; q < 5; ++q) row[q] = boxes[src*5+q];
        row[5] = s;
        out[NB*DET*6 + b*DET + r] = (float)(f / NPROP + 1);
    }
}

extern "C" void kernel_launch(void* const* d_in, const int* in_sizes, int n_in,
                              void* d_out, int out_size, void* d_ws, size_t ws_size,
                              hipStream_t stream) {
    const float* logits = (const float*)d_in[0];
    const float* boxreg = (const float*)d_in[1];
    const float* rrects = (const float*)d_in[2];
    float* out = (float*)d_out;
    float* ws  = (float*)d_ws;
    (void)in_sizes; (void)n_in; (void)out_size; (void)ws_size;

    prep_kernel<<<(M_TOTAL + 255) / 256, 256, 0, stream>>>(logits, boxreg, rrects, ws, out);
    compact_kernel<<<BC_TOTAL, NPROP, 0, stream>>>(ws);
    heavy_kernel<<<(BC_TOTAL * NPROP * 6 * 64) / 256, 256, 0, stream>>>(ws);
    nms_kernel<<<BC_TOTAL, NPROP, 0, stream>>>(ws);
    topk_kernel<<<NB * 16, 256, 0, stream>>>(ws, out);
}

// Round 6
// 170.576 us; speedup vs baseline: 5.2220x; 1.1878x over previous
//
#include <hip/hip_runtime.h>
#include <cmath>

#define NPROP 384
#define NB 2
#define NCLS 11
#define NFG 10
#define BC_TOTAL (NB*NFG)          // 20
#define M_TOTAL (NB*NPROP)         // 768
#define FLAT_PER_IMG (NFG*NPROP)   // 3840
#define DET 100

// ws layout (in 4-byte words) — total 222784 words = 891 KB (proven footprint)
#define OFF_BOXES 0                // [BC][N][5]  38400
#define OFF_AREA  38400            // [BC][N]     7680
#define OFF_SCORE 46080            // [BC][N]     7680
#define OFF_VIDX  53760            // [BC][N]     7680  valid idx; later kept flat idx [NB][FLAT]
#define OFF_SUP   61440            // [BC][N][12] 92160 (u32 suppress bitrows)
#define OFF_MS    153600           // [B][FLAT]   7680  kept scores (compacted)
#define OFF_VCNT  161280           // [0..19] valid counts; [24..25] kept counts; [32] pair counter
#define OFF_PAIRS 161344           // pair list, capacity 61440 u32
#define PAIR_CAP  61440

__device__ __forceinline__ void mk_corners(float px, float py, float pw, float ph, float pa,
                                           float cxo[4], float cyo[4]) {
    float t = pa * 0.017453292519943295f;
    float ct = cosf(t), st = sinf(t);
    float hx = pw*0.5f, hy = ph*0.5f;
    float lx[4] = {-hx, hx, hx, -hx};
    float ly[4] = {-hy, -hy, hy, hy};
#pragma unroll
    for (int k = 0; k < 4; ++k) {
        cxo[k] = px + lx[k]*ct - ly[k]*st;
        cyo[k] = py + lx[k]*st + ly[k]*ct;
    }
}

__device__ float inter_area_net(const float ax[4], const float ay[4],
                                const float bx[4], const float by[4]) {
    float d1x[4], d1y[4], d2x[4], d2y[4];
#pragma unroll
    for (int k = 0; k < 4; ++k) {
        int k1 = (k + 1) & 3;
        d1x[k] = ax[k1] - ax[k]; d1y[k] = ay[k1] - ay[k];
        d2x[k] = bx[k1] - bx[k]; d2y[k] = by[k1] - by[k];
    }
    float ex[32], ey[32];
    bool msk[24];
#pragma unroll
    for (int i = 0; i < 4; ++i) {
#pragma unroll
        for (int j = 0; j < 4; ++j) {
            float den = d1x[i]*d2y[j] - d1y[i]*d2x[j];
            float dfx = bx[j]-ax[i], dfy = by[j]-ay[i];
            float dens = (fabsf(den) < 1e-8f) ? 1.0f : den;
            float t = (dfx*d2y[j] - dfy*d2x[j]) / dens;
            float u = (dfx*d1y[i] - dfy*d1x[i]) / dens;
            bool ok = (fabsf(den) >= 1e-8f) && t >= 0.0f && t <= 1.0f
                                            && u >= 0.0f && u <= 1.0f;
            ex[i*4+j] = ax[i] + t*d1x[i];
            ey[i*4+j] = ay[i] + t*d1y[i];
            msk[i*4+j] = ok;
        }
    }
#pragma unroll
    for (int i = 0; i < 4; ++i) {   // corners of A inside B
        bool allp = true, alln = true;
#pragma unroll
        for (int j = 0; j < 4; ++j) {
            float cr = d2x[j]*(ay[i]-by[j]) - d2y[j]*(ax[i]-bx[j]);
            allp = allp && (cr >= -1e-6f);
            alln = alln && (cr <= 1e-6f);
        }
        ex[16+i] = ax[i]; ey[16+i] = ay[i]; msk[16+i] = allp || alln;
    }
#pragma unroll
    for (int i = 0; i < 4; ++i) {   // corners of B inside A
        bool allp = true, alln = true;
#pragma unroll
        for (int j = 0; j < 4; ++j) {
            float cr = d1x[j]*(by[i]-ay[j]) - d1y[j]*(bx[i]-ax[j]);
            allp = allp && (cr >= -1e-6f);
            alln = alln && (cr <= 1e-6f);
        }
        ex[20+i] = bx[i]; ey[20+i] = by[i]; msk[20+i] = allp || alln;
    }
    int nv = 0; float sx = 0.f, sy = 0.f;
#pragma unroll
    for (int k = 0; k < 24; ++k)
        if (msk[k]) { nv++; sx += ex[k]; sy += ey[k]; }
    float fm = (float)(nv > 1 ? nv : 1);
    float cx = sx / fm, cy = sy / fm;
    unsigned key[32];
#pragma unroll
    for (int k = 0; k < 24; ++k) {
        float qx = msk[k] ? ex[k] : cx;
        float qy = msk[k] ? ey[k] : cy;
        ex[k] = qx; ey[k] = qy;
        float dx = qx - cx, dy = qy - cy;        // parked: dx=dy=+0
        float den = fabsf(dx) + fabsf(dy);
        float r = (den > 0.0f) ? dy / den : 0.0f;
        float p = (dx >= 0.0f) ? r : ((dy >= 0.0f) ? 2.0f - r : -2.0f - r);
        p = p + 0.0f;                             // canonicalize -0 -> +0
        unsigned u = __float_as_uint(p);
        u = (u & 0x80000000u) ? ~u : (u | 0x80000000u);
        key[k] = (u & 0xFFFFFFE0u) | (unsigned)k;
    }
#pragma unroll
    for (int k = 24; k < 32; ++k) { key[k] = 0xFFFFFFFFu; ex[k] = 0.f; ey[k] = 0.f; }
    // bitonic sort, 32 elements ascending, fully unrolled (static idx -> VGPRs)
#pragma unroll
    for (int k = 2; k <= 32; k <<= 1) {
#pragma unroll
        for (int j = k >> 1; j > 0; j >>= 1) {
#pragma unroll
            for (int i = 0; i < 32; ++i) {
                int l = i ^ j;
                if (l > i) {
                    bool up = ((i & k) == 0);
                    unsigned ka = key[i], kb = key[l];
                    bool sw = up ? (ka > kb) : (ka < kb);
                    float xa = ex[i], xb = ex[l];
                    float ya = ey[i], yb = ey[l];
                    key[i] = sw ? kb : ka; key[l] = sw ? ka : kb;
                    ex[i]  = sw ? xb : xa; ex[l]  = sw ? xa : xb;
                    ey[i]  = sw ? yb : ya; ey[l]  = sw ? ya : yb;
                }
            }
        }
    }
    float s = 0.f;
#pragma unroll
    for (int k = 0; k < 24; ++k) {
        int n = (k + 1 == 24) ? 0 : (k + 1);
        s += ex[k]*ey[n] - ey[k]*ex[n];
    }
    float area = 0.5f * fabsf(s);
    return (nv >= 3) ? area : 0.0f;
}

// full pair evaluation: corners from boxes (identical formula everywhere),
// inter_area(c_hi, c_lo), set suppress bit (hi row, lo col) if iou > 0.5
__device__ __forceinline__ void eval_pair(float* ws, int bc, int hi, int lo) {
    const float* boxes = ws + OFF_BOXES;
    const float* areaA = ws + OFF_AREA;
    unsigned int* supw = (unsigned int*)(ws + OFF_SUP);
    int rowi = bc*NPROP + hi, rowj = bc*NPROP + lo;
    float axp[4], ayp[4], bxp[4], byp[4];
    mk_corners(boxes[rowi*5+0], boxes[rowi*5+1], boxes[rowi*5+2],
               boxes[rowi*5+3], boxes[rowi*5+4], axp, ayp);
    mk_corners(boxes[rowj*5+0], boxes[rowj*5+1], boxes[rowj*5+2],
               boxes[rowj*5+3], boxes[rowj*5+4], bxp, byp);
    float inter = inter_area_net(axp, ayp, bxp, byp);
    float iou = inter / (areaA[rowi] + areaA[rowj] - inter + 1e-8f);
    if (iou > 0.5f)
        atomicOr(&supw[rowi*12 + (lo >> 5)], 1u << (lo & 31));
}

__global__ __launch_bounds__(256)
void prep_kernel(const float* __restrict__ logits,
                 const float* __restrict__ boxreg,
                 const float* __restrict__ rrects,
                 float* __restrict__ ws,
                 float* __restrict__ out) {
    int m = blockIdx.x * blockDim.x + threadIdx.x;
    if (m >= M_TOTAL) return;
    out[m] = 0.0f;                               // zero 1400-float output
    if (m + M_TOTAL < NB*DET*6 + NB*DET) out[m + M_TOTAL] = 0.0f;
    int b = m / NPROP, n = m % NPROP;
    float lg[NCLS];
    float mx = -INFINITY;
#pragma unroll
    for (int c = 0; c < NCLS; ++c) { lg[c] = logits[m*NCLS+c]; mx = fmaxf(mx, lg[c]); }
    float exo[NCLS]; float sum = 0.f;
#pragma unroll
    for (int c = 0; c < NCLS; ++c) { exo[c] = expf(lg[c]-mx); sum += exo[c]; }
    float axc = rrects[m*5+0], ayc = rrects[m*5+1];
    float aw  = rrects[m*5+2], ah  = rrects[m*5+3], aa = rrects[m*5+4];
    float* boxes = ws + OFF_BOXES;
    float* areaA = ws + OFF_AREA;
    float* scoreA= ws + OFF_SCORE;
    for (int cls = 1; cls < NCLS; ++cls) {
        int o = ((b*NFG + (cls-1))*NPROP + n);
        float prob = exo[cls] / sum;
        const float* rel = boxreg + m*(NCLS*5) + cls*5;
        float dx = rel[0] / 10.0f;
        float dy = rel[1] / 10.0f;
        float dw = fminf(rel[2] / 5.0f, 4.1351665567423205f);
        float dh = fminf(rel[3] / 5.0f, 4.1351665567423205f);
        float da = rel[4];
        float px = dx*aw + axc;
        float py = dy*ah + ayc;
        float pw = expf(dw)*aw;
        float ph = expf(dh)*ah;
        float pa = da*57.29577951308232f + aa;
        float xm = pa + 180.0f;
        float r = fmodf(xm, 360.0f);
        if (r < 0.0f) r += 360.0f;
        pa = r - 180.0f;
        boxes[o*5+0]=px; boxes[o*5+1]=py; boxes[o*5+2]=pw; boxes[o*5+3]=ph; boxes[o*5+4]=pa;
        areaA[o]  = pw*ph;
        scoreA[o] = prob;
    }
}

// zero suppress bitrows + counters + compact valid indices per (b,cls)
__global__ __launch_bounds__(384)
void compact_kernel(float* __restrict__ ws) {
    __shared__ int cntS;
    int bc = blockIdx.x, t = threadIdx.x;
    unsigned int* supw = (unsigned int*)(ws + OFF_SUP);
    unsigned int* vidx = (unsigned int*)(ws + OFF_VIDX);
    unsigned int* vcnt = (unsigned int*)(ws + OFF_VCNT);
    int r0 = (bc*NPROP + t)*12;
#pragma unroll
    for (int w = 0; w < 12; ++w) supw[r0 + w] = 0u;
    if (t == 0) cntS = 0;
    if (bc == 0 && t < NB) vcnt[24 + t] = 0u;    // kept-list counters
    if (bc == 0 && t == 32) vcnt[32] = 0u;       // pair counter
    __syncthreads();
    float sc = ws[OFF_SCORE + bc*NPROP + t];
    if (sc > 0.05f) {
        int p = atomicAdd(&cntS, 1);
        vidx[bc*NPROP + p] = (unsigned)t;
    }
    __syncthreads();
    if (t == 0) vcnt[bc] = (unsigned)cntS;
}

// enumerate unordered valid pairs, cull, orient (hi-rank -> lo-rank),
// ballot-compact survivors into the global pair list
__global__ __launch_bounds__(256)
void pairgen_kernel(float* __restrict__ ws) {
    const float* boxes = ws + OFF_BOXES;
    const float* areaA = ws + OFF_AREA;
    const float* scoreA = ws + OFF_SCORE;
    const unsigned int* vidx = (const unsigned int*)(ws + OFF_VIDX);
    const unsigned int* vcnt = (const unsigned int*)(ws + OFF_VCNT);
    unsigned int* pcnt = (unsigned int*)(ws + OFF_VCNT) + 32;
    unsigned int* pairs = (unsigned int*)(ws + OFF_PAIRS);
    int wave = (blockIdx.x * blockDim.x + threadIdx.x) >> 6;
    int lane = threadIdx.x & 63;
    int bw = wave % 6;
    int a  = (wave / 6) % NPROP;
    int bc = wave / (6 * NPROP);
    if (bc >= BC_TOTAL) return;
    int cnt = (int)vcnt[bc];
    if (a >= cnt || bw*64 >= cnt) return;        // wave-uniform exits
    int i = (int)vidx[bc*NPROP + a];
    int rowi = bc*NPROP + i;
    int b = bw*64 + lane;
    bool go = (b < cnt) && (b > a);              // unordered pairs once
    int j = go ? (int)vidx[bc*NPROP + b] : i;
    int rowj = bc*NPROP + j;
    if (go) {
        float cxi = boxes[rowi*5+0], cyi = boxes[rowi*5+1];
        float wi  = boxes[rowi*5+2], hi  = boxes[rowi*5+3];
        float cxj = boxes[rowj*5+0], cyj = boxes[rowj*5+1];
        float wj  = boxes[rowj*5+2], hj  = boxes[rowj*5+3];
        float ddx = cxi-cxj, ddy = cyi-cyj;
        float rr = 0.5f*sqrtf(wi*wi+hi*hi) + 0.5f*sqrtf(wj*wj+hj*hj);
        go = (ddx*ddx + ddy*ddy <= rr*rr);
        if (go) {
            float A = areaA[rowi], Bv = areaA[rowj];
            float mn = fminf(A, Bv);
            go = (3.0f*mn > A + Bv);             // else iou <= 0.5 provably
        }
    }
    // orient: hi = earlier in NMS order (score desc, idx asc)
    float si = scoreA[rowi], sj = scoreA[rowj];
    bool ifirst = (si > sj) || (si == sj && i < j);
    int hi = ifirst ? i : j;
    int lo = ifirst ? j : i;
    unsigned long long m = __ballot(go);
    unsigned base = 0;
    if (lane == 0 && m) base = atomicAdd(pcnt, (unsigned)__popcll(m));
    base = __shfl(base, 0);
    if (go) {
        unsigned pos = base + (unsigned)__popcll(m & ((1ull << lane) - 1ull));
        if (pos < PAIR_CAP)
            pairs[pos] = ((unsigned)bc << 20) | ((unsigned)hi << 10) | (unsigned)lo;
        else
            eval_pair(ws, bc, hi, lo);           // overflow fallback (never in practice)
    }
}

// one lane per surviving pair — full 64-lane utilization
__global__ __launch_bounds__(256)
void pairheavy_kernel(float* __restrict__ ws) {
    const unsigned int* pcnt = (const unsigned int*)(ws + OFF_VCNT) + 32;
    const unsigned int* pairs = (const unsigned int*)(ws + OFF_PAIRS);
    unsigned n = *pcnt;
    if (n > PAIR_CAP) n = PAIR_CAP;
    unsigned stride = gridDim.x * blockDim.x;
    for (unsigned p = blockIdx.x * blockDim.x + threadIdx.x; p < n; p += stride) {
        unsigned pk = pairs[p];
        int bc = (int)(pk >> 20);
        int hi = (int)((pk >> 10) & 0x3FF);
        int lo = (int)(pk & 0x3FF);
        eval_pair(ws, bc, hi, lo);
    }
}

__global__ __launch_bounds__(384)
void nms_kernel(float* __restrict__ ws) {
    __shared__ float scoreL[NPROP];
    __shared__ int orderL[NPROP];
    __shared__ unsigned int supL[NPROP*12];   // 18.4 KB
    __shared__ unsigned char keepS[NPROP];
    __shared__ int nvalidS;
    int bc = blockIdx.x;
    const float* scoreA = ws + OFF_SCORE;
    const unsigned int* supbG = (const unsigned int*)(ws + OFF_SUP);
    unsigned int* kidxG = (unsigned int*)(ws + OFF_VIDX);   // kept flat idx [NB][FLAT]
    float* kscG = ws + OFF_MS;                              // kept scores [NB][FLAT]
    unsigned int* kcntG = (unsigned int*)(ws + OFF_VCNT) + 24;
    int t = threadIdx.x;
    if (t == 0) nvalidS = 0;
    scoreL[t] = scoreA[bc*NPROP+t];
    keepS[t] = 0;
    __syncthreads();
    {
        bool vi = scoreL[t] > 0.05f;
        float si = vi ? scoreL[t] : -INFINITY;
        int r = 0;
        for (int k = 0; k < NPROP; ++k) {
            bool vk = scoreL[k] > 0.05f;
            float sk = vk ? scoreL[k] : -INFINITY;
            r += (sk > si) || (sk == si && k < t);
        }
        orderL[r] = t;
        if (vi) atomicAdd(&nvalidS, 1);
    }
    for (int k = t; k < NPROP*12; k += NPROP) supL[k] = supbG[bc*NPROP*12 + k];
    __syncthreads();
    if (t == 0) {
        unsigned int sup[12];
#pragma unroll
        for (int w = 0; w < 12; ++w) sup[w] = 0u;
        int NV = nvalidS;
        for (int p = 0; p < NV; ++p) {      // valid entries sort first
            int o = orderL[p];
            if (!((sup[o>>5] >> (o & 31)) & 1u)) {
                keepS[o] = 1;
#pragma unroll
                for (int w = 0; w < 12; ++w) sup[w] |= supL[o*12 + w];
            }
        }
    }
    __syncthreads();
    // compact kept boxes into per-image list (rank formula is order-independent)
    if (keepS[t]) {
        int img = bc / NFG;
        int f = (bc % NFG) * NPROP + t;
        int pos = (int)atomicAdd(&kcntG[img], 1u);
        kidxG[img*FLAT_PER_IMG + pos] = (unsigned)f;
        kscG [img*FLAT_PER_IMG + pos] = scoreL[t];
    }
}

// 16 blocks per image; kept list as u64 keys in LDS; unroll-16 rank count.
// key = (score_bits << 32) | (~f): u64 compare == (score desc, f asc).
__global__ __launch_bounds__(256)
void topk_kernel(const float* __restrict__ ws, float* __restrict__ out) {
    __shared__ unsigned long long keyL[FLAT_PER_IMG];
    int b = blockIdx.x >> 4;
    int slice = blockIdx.x & 15;
    int t = threadIdx.x;
    const unsigned int* kidxG = (const unsigned int*)(ws + OFF_VIDX);
    const float* kscG = ws + OFF_MS;
    const unsigned int* kcntG = (const unsigned int*)(ws + OFF_VCNT) + 24;
    const float* boxes = ws + OFF_BOXES;
    int K = (int)kcntG[b];
    int KP = (K + 15) & ~15;
    for (int k = t; k < KP; k += 256) {
        unsigned long long key = 0ull;
        if (k < K) {
            unsigned sb = __float_as_uint(kscG[b*FLAT_PER_IMG + k]);
            unsigned f  = kidxG[b*FLAT_PER_IMG + k];
            key = ((unsigned long long)sb << 32) | (unsigned long long)(0xFFFFFFFFu - f);
        }
        keyL[k] = key;
    }
    __syncthreads();
    int e = slice*256 + t;
    if (e >= K) return;
    unsigned long long my = keyL[e];
    int r = 0;
    for (int k = 0; k < KP; k += 16) {
        int acc = 0;
#pragma unroll
        for (int q = 0; q < 16; ++q)
            acc += (keyL[k+q] > my) ? 1 : 0;
        r += acc;
    }
    if (r < DET) {
        unsigned f = 0xFFFFFFFFu - (unsigned)(my & 0xFFFFFFFFu);
        float s = __uint_as_float((unsigned)(my >> 32));
        int src = b*FLAT_PER_IMG + (int)f;
        float* row = out + (b*DET + r)*6;
#pragma unroll
        for (int q = 0; q < 5; ++q) row[q] = boxes[src*5+q];
        row[5] = s;
        out[NB*DET*6 + b*DET + r] = (float)(f / NPROP + 1);
    }
}

extern "C" void kernel_launch(void* const* d_in, const int* in_sizes, int n_in,
                              void* d_out, int out_size, void* d_ws, size_t ws_size,
                              hipStream_t stream) {
    const float* logits = (const float*)d_in[0];
    const float* boxreg = (const float*)d_in[1];
    const float* rrects = (const float*)d_in[2];
    float* out = (float*)d_out;
    float* ws  = (float*)d_ws;
    (void)in_sizes; (void)n_in; (void)out_size; (void)ws_size;

    prep_kernel<<<(M_TOTAL + 255) / 256, 256, 0, stream>>>(logits, boxreg, rrects, ws, out);
    compact_kernel<<<BC_TOTAL, NPROP, 0, stream>>>(ws);
    pairgen_kernel<<<(BC_TOTAL * NPROP * 6 * 64) / 256, 256, 0, stream>>>(ws);
    pairheavy_kernel<<<256, 256, 0, stream>>>(ws);
    nms_kernel<<<BC_TOTAL, NPROP, 0, stream>>>(ws);
    topk_kernel<<<NB * 16, 256, 0, stream>>>(ws, out);
}

// Round 7
// 160.088 us; speedup vs baseline: 5.5641x; 1.0655x over previous
//
#include <hip/hip_runtime.h>
#include <cmath>

#define NPROP 384
#define NB 2
#define NCLS 11
#define NFG 10
#define BC_TOTAL (NB*NFG)          // 20
#define M_TOTAL (NB*NPROP)         // 768
#define FLAT_PER_IMG (NFG*NPROP)   // 3840
#define DET 100

// ws layout (in 4-byte words) — total 222784 words = 891 KB (proven footprint)
#define OFF_BOXES 0                // [BC][N][5]  38400
#define OFF_AREA  38400            // [BC][N]     7680
#define OFF_SCORE 46080            // [BC][N]     7680
#define OFF_VIDX  53760            // [BC][N]     7680  valid idx; later kept flat idx [NB][FLAT]
#define OFF_SUP   61440            // [BC][N][12] 92160 (u32 suppress bitrows; 8B-aligned)
#define OFF_MS    153600           // [B][FLAT]   7680  kept scores (compacted)
#define OFF_VCNT  161280           // [0..19] valid counts; [24..25] kept counts; [32] pair counter
#define OFF_PAIRS 161344           // pair list, capacity 61440 u32
#define PAIR_CAP  61440

typedef unsigned long long ull;

__device__ __forceinline__ void mk_corners(float px, float py, float pw, float ph, float pa,
                                           float cxo[4], float cyo[4]) {
    float t = pa * 0.017453292519943295f;
    float ct = cosf(t), st = sinf(t);
    float hx = pw*0.5f, hy = ph*0.5f;
    float lx[4] = {-hx, hx, hx, -hx};
    float ly[4] = {-hy, -hy, hy, hy};
#pragma unroll
    for (int k = 0; k < 4; ++k) {
        cxo[k] = px + lx[k]*ct - ly[k]*st;
        cyo[k] = py + lx[k]*st + ly[k]*ct;
    }
}

__device__ float inter_area_net(const float ax[4], const float ay[4],
                                const float bx[4], const float by[4]) {
    float d1x[4], d1y[4], d2x[4], d2y[4];
#pragma unroll
    for (int k = 0; k < 4; ++k) {
        int k1 = (k + 1) & 3;
        d1x[k] = ax[k1] - ax[k]; d1y[k] = ay[k1] - ay[k];
        d2x[k] = bx[k1] - bx[k]; d2y[k] = by[k1] - by[k];
    }
    float ex[32], ey[32];
    bool msk[24];
#pragma unroll
    for (int i = 0; i < 4; ++i) {
#pragma unroll
        for (int j = 0; j < 4; ++j) {
            float den = d1x[i]*d2y[j] - d1y[i]*d2x[j];
            float dfx = bx[j]-ax[i], dfy = by[j]-ay[i];
            float dens = (fabsf(den) < 1e-8f) ? 1.0f : den;
            float t = (dfx*d2y[j] - dfy*d2x[j]) / dens;
            float u = (dfx*d1y[i] - dfy*d1x[i]) / dens;
            bool ok = (fabsf(den) >= 1e-8f) && t >= 0.0f && t <= 1.0f
                                            && u >= 0.0f && u <= 1.0f;
            ex[i*4+j] = ax[i] + t*d1x[i];
            ey[i*4+j] = ay[i] + t*d1y[i];
            msk[i*4+j] = ok;
        }
    }
#pragma unroll
    for (int i = 0; i < 4; ++i) {   // corners of A inside B
        bool allp = true, alln = true;
#pragma unroll
        for (int j = 0; j < 4; ++j) {
            float cr = d2x[j]*(ay[i]-by[j]) - d2y[j]*(ax[i]-bx[j]);
            allp = allp && (cr >= -1e-6f);
            alln = alln && (cr <= 1e-6f);
        }
        ex[16+i] = ax[i]; ey[16+i] = ay[i]; msk[16+i] = allp || alln;
    }
#pragma unroll
    for (int i = 0; i < 4; ++i) {   // corners of B inside A
        bool allp = true, alln = true;
#pragma unroll
        for (int j = 0; j < 4; ++j) {
            float cr = d1x[j]*(by[i]-ay[j]) - d1y[j]*(bx[i]-ax[j]);
            allp = allp && (cr >= -1e-6f);
            alln = alln && (cr <= 1e-6f);
        }
        ex[20+i] = bx[i]; ey[20+i] = by[i]; msk[20+i] = allp || alln;
    }
    int nv = 0; float sx = 0.f, sy = 0.f;
#pragma unroll
    for (int k = 0; k < 24; ++k)
        if (msk[k]) { nv++; sx += ex[k]; sy += ey[k]; }
    float fm = (float)(nv > 1 ? nv : 1);
    float cx = sx / fm, cy = sy / fm;
    unsigned key[32];
#pragma unroll
    for (int k = 0; k < 24; ++k) {
        float qx = msk[k] ? ex[k] : cx;
        float qy = msk[k] ? ey[k] : cy;
        ex[k] = qx; ey[k] = qy;
        float dx = qx - cx, dy = qy - cy;        // parked: dx=dy=+0
        float den = fabsf(dx) + fabsf(dy);
        float r = (den > 0.0f) ? dy / den : 0.0f;
        float p = (dx >= 0.0f) ? r : ((dy >= 0.0f) ? 2.0f - r : -2.0f - r);
        p = p + 0.0f;                             // canonicalize -0 -> +0
        unsigned u = __float_as_uint(p);
        u = (u & 0x80000000u) ? ~u : (u | 0x80000000u);
        key[k] = (u & 0xFFFFFFE0u) | (unsigned)k;
    }
#pragma unroll
    for (int k = 24; k < 32; ++k) { key[k] = 0xFFFFFFFFu; ex[k] = 0.f; ey[k] = 0.f; }
    // bitonic sort, 32 elements ascending, fully unrolled (static idx -> VGPRs)
#pragma unroll
    for (int k = 2; k <= 32; k <<= 1) {
#pragma unroll
        for (int j = k >> 1; j > 0; j >>= 1) {
#pragma unroll
            for (int i = 0; i < 32; ++i) {
                int l = i ^ j;
                if (l > i) {
                    bool up = ((i & k) == 0);
                    unsigned ka = key[i], kb = key[l];
                    bool sw = up ? (ka > kb) : (ka < kb);
                    float xa = ex[i], xb = ex[l];
                    float ya = ey[i], yb = ey[l];
                    key[i] = sw ? kb : ka; key[l] = sw ? ka : kb;
                    ex[i]  = sw ? xb : xa; ex[l]  = sw ? xa : xb;
                    ey[i]  = sw ? yb : ya; ey[l]  = sw ? ya : yb;
                }
            }
        }
    }
    float s = 0.f;
#pragma unroll
    for (int k = 0; k < 24; ++k) {
        int n = (k + 1 == 24) ? 0 : (k + 1);
        s += ex[k]*ey[n] - ey[k]*ex[n];
    }
    float area = 0.5f * fabsf(s);
    return (nv >= 3) ? area : 0.0f;
}

// full pair evaluation: corners from boxes (identical formula everywhere),
// inter_area(c_hi, c_lo), set suppress bit (hi row, lo col) if iou > 0.5
__device__ __forceinline__ void eval_pair(float* ws, int bc, int hi, int lo) {
    const float* boxes = ws + OFF_BOXES;
    const float* areaA = ws + OFF_AREA;
    unsigned int* supw = (unsigned int*)(ws + OFF_SUP);
    int rowi = bc*NPROP + hi, rowj = bc*NPROP + lo;
    float axp[4], ayp[4], bxp[4], byp[4];
    mk_corners(boxes[rowi*5+0], boxes[rowi*5+1], boxes[rowi*5+2],
               boxes[rowi*5+3], boxes[rowi*5+4], axp, ayp);
    mk_corners(boxes[rowj*5+0], boxes[rowj*5+1], boxes[rowj*5+2],
               boxes[rowj*5+3], boxes[rowj*5+4], bxp, byp);
    float inter = inter_area_net(axp, ayp, bxp, byp);
    float iou = inter / (areaA[rowi] + areaA[rowj] - inter + 1e-8f);
    if (iou > 0.5f)
        atomicOr(&supw[rowi*12 + (lo >> 5)], 1u << (lo & 31));
}

__global__ __launch_bounds__(256)
void prep_kernel(const float* __restrict__ logits,
                 const float* __restrict__ boxreg,
                 const float* __restrict__ rrects,
                 float* __restrict__ ws,
                 float* __restrict__ out) {
    int m = blockIdx.x * blockDim.x + threadIdx.x;
    if (m >= M_TOTAL) return;
    out[m] = 0.0f;                               // zero 1400-float output
    if (m + M_TOTAL < NB*DET*6 + NB*DET) out[m + M_TOTAL] = 0.0f;
    int b = m / NPROP, n = m % NPROP;
    float lg[NCLS];
    float mx = -INFINITY;
#pragma unroll
    for (int c = 0; c < NCLS; ++c) { lg[c] = logits[m*NCLS+c]; mx = fmaxf(mx, lg[c]); }
    float exo[NCLS]; float sum = 0.f;
#pragma unroll
    for (int c = 0; c < NCLS; ++c) { exo[c] = expf(lg[c]-mx); sum += exo[c]; }
    float axc = rrects[m*5+0], ayc = rrects[m*5+1];
    float aw  = rrects[m*5+2], ah  = rrects[m*5+3], aa = rrects[m*5+4];
    float* boxes = ws + OFF_BOXES;
    float* areaA = ws + OFF_AREA;
    float* scoreA= ws + OFF_SCORE;
    for (int cls = 1; cls < NCLS; ++cls) {
        int o = ((b*NFG + (cls-1))*NPROP + n);
        float prob = exo[cls] / sum;
        const float* rel = boxreg + m*(NCLS*5) + cls*5;
        float dx = rel[0] / 10.0f;
        float dy = rel[1] / 10.0f;
        float dw = fminf(rel[2] / 5.0f, 4.1351665567423205f);
        float dh = fminf(rel[3] / 5.0f, 4.1351665567423205f);
        float da = rel[4];
        float px = dx*aw + axc;
        float py = dy*ah + ayc;
        float pw = expf(dw)*aw;
        float ph = expf(dh)*ah;
        float pa = da*57.29577951308232f + aa;
        float xm = pa + 180.0f;
        float r = fmodf(xm, 360.0f);
        if (r < 0.0f) r += 360.0f;
        pa = r - 180.0f;
        boxes[o*5+0]=px; boxes[o*5+1]=py; boxes[o*5+2]=pw; boxes[o*5+3]=ph; boxes[o*5+4]=pa;
        areaA[o]  = pw*ph;
        scoreA[o] = prob;
    }
}

// zero suppress bitrows + counters + compact valid indices per (b,cls)
__global__ __launch_bounds__(384)
void compact_kernel(float* __restrict__ ws) {
    __shared__ int cntS;
    int bc = blockIdx.x, t = threadIdx.x;
    unsigned int* supw = (unsigned int*)(ws + OFF_SUP);
    unsigned int* vidx = (unsigned int*)(ws + OFF_VIDX);
    unsigned int* vcnt = (unsigned int*)(ws + OFF_VCNT);
    int r0 = (bc*NPROP + t)*12;
#pragma unroll
    for (int w = 0; w < 12; ++w) supw[r0 + w] = 0u;
    if (t == 0) cntS = 0;
    if (bc == 0 && t < NB) vcnt[24 + t] = 0u;    // kept-list counters
    if (bc == 0 && t == 32) vcnt[32] = 0u;       // pair counter
    __syncthreads();
    float sc = ws[OFF_SCORE + bc*NPROP + t];
    if (sc > 0.05f) {
        int p = atomicAdd(&cntS, 1);
        vidx[bc*NPROP + p] = (unsigned)t;
    }
    __syncthreads();
    if (t == 0) vcnt[bc] = (unsigned)cntS;
}

// enumerate unordered valid pairs, cull, orient (hi-rank -> lo-rank),
// ballot-compact survivors into the global pair list
__global__ __launch_bounds__(256)
void pairgen_kernel(float* __restrict__ ws) {
    const float* boxes = ws + OFF_BOXES;
    const float* areaA = ws + OFF_AREA;
    const float* scoreA = ws + OFF_SCORE;
    const unsigned int* vidx = (const unsigned int*)(ws + OFF_VIDX);
    const unsigned int* vcnt = (const unsigned int*)(ws + OFF_VCNT);
    unsigned int* pcnt = (unsigned int*)(ws + OFF_VCNT) + 32;
    unsigned int* pairs = (unsigned int*)(ws + OFF_PAIRS);
    int wave = (blockIdx.x * blockDim.x + threadIdx.x) >> 6;
    int lane = threadIdx.x & 63;
    int bw = wave % 6;
    int a  = (wave / 6) % NPROP;
    int bc = wave / (6 * NPROP);
    if (bc >= BC_TOTAL) return;
    int cnt = (int)vcnt[bc];
    if (a >= cnt || bw*64 >= cnt) return;        // wave-uniform exits
    int i = (int)vidx[bc*NPROP + a];
    int rowi = bc*NPROP + i;
    int b = bw*64 + lane;
    bool go = (b < cnt) && (b > a);              // unordered pairs once
    int j = go ? (int)vidx[bc*NPROP + b] : i;
    int rowj = bc*NPROP + j;
    if (go) {
        float cxi = boxes[rowi*5+0], cyi = boxes[rowi*5+1];
        float wi  = boxes[rowi*5+2], hi  = boxes[rowi*5+3];
        float cxj = boxes[rowj*5+0], cyj = boxes[rowj*5+1];
        float wj  = boxes[rowj*5+2], hj  = boxes[rowj*5+3];
        float ddx = cxi-cxj, ddy = cyi-cyj;
        float rr = 0.5f*sqrtf(wi*wi+hi*hi) + 0.5f*sqrtf(wj*wj+hj*hj);
        go = (ddx*ddx + ddy*ddy <= rr*rr);
        if (go) {
            float A = areaA[rowi], Bv = areaA[rowj];
            float mn = fminf(A, Bv);
            go = (3.0f*mn > A + Bv);             // else iou <= 0.5 provably
        }
    }
    // orient: hi = earlier in NMS order (score desc, idx asc)
    float si = scoreA[rowi], sj = scoreA[rowj];
    bool ifirst = (si > sj) || (si == sj && i < j);
    int hi = ifirst ? i : j;
    int lo = ifirst ? j : i;
    unsigned long long m = __ballot(go);
    unsigned base = 0;
    if (lane == 0 && m) base = atomicAdd(pcnt, (unsigned)__popcll(m));
    base = __shfl(base, 0);
    if (go) {
        unsigned pos = base + (unsigned)__popcll(m & ((1ull << lane) - 1ull));
        if (pos < PAIR_CAP)
            pairs[pos] = ((unsigned)bc << 20) | ((unsigned)hi << 10) | (unsigned)lo;
        else
            eval_pair(ws, bc, hi, lo);           // overflow fallback (never in practice)
    }
}

// one lane per surviving pair — full 64-lane utilization
__global__ __launch_bounds__(256)
void pairheavy_kernel(float* __restrict__ ws) {
    const unsigned int* pcnt = (const unsigned int*)(ws + OFF_VCNT) + 32;
    const unsigned int* pairs = (const unsigned int*)(ws + OFF_PAIRS);
    unsigned n = *pcnt;
    if (n > PAIR_CAP) n = PAIR_CAP;
    unsigned stride = gridDim.x * blockDim.x;
    for (unsigned p = blockIdx.x * blockDim.x + threadIdx.x; p < n; p += stride) {
        unsigned pk = pairs[p];
        int bc = (int)(pk >> 20);
        int hi = (int)((pk >> 10) & 0x3FF);
        int lo = (int)(pk & 0x3FF);
        eval_pair(ws, bc, hi, lo);
    }
}

// wave-parallel greedy NMS: sorted order via u64-key rank count; suppressed
// set lives in registers of wave 0 (lanes 0..5 hold 64 bits each); row fetch
// and order fetch are prefetched (independent of keep decisions) so the
// serial chain is only bit-test -> ballot -> or.
__global__ __launch_bounds__(384)
void nms_kernel(float* __restrict__ ws) {
    __shared__ ull keyL[NPROP];            // 3 KB
    __shared__ int orderL[NPROP];
    __shared__ ull supL[NPROP*6];          // 18.4 KB (u64 rows, original-index space)
    __shared__ unsigned char keepS[NPROP];
    __shared__ int nvalidS;
    int bc = blockIdx.x, t = threadIdx.x;
    const float* scoreA = ws + OFF_SCORE;
    const ull* supG = (const ull*)((const unsigned int*)(ws + OFF_SUP));
    unsigned int* kidxG = (unsigned int*)(ws + OFF_VIDX);   // kept flat idx [NB][FLAT]
    float* kscG = ws + OFF_MS;                              // kept scores [NB][FLAT]
    unsigned int* kcntG = (unsigned int*)(ws + OFF_VCNT) + 24;
    if (t == 0) nvalidS = 0;
    float sc = scoreA[bc*NPROP + t];
    bool vi = sc > 0.05f;
    // key: valid -> (scorebits, ~t); invalid -> (0, ~t). desc-u64 == NMS order.
    ull myk = vi ? (((ull)__float_as_uint(sc) << 32) | (ull)(0xFFFFFFFFu - (unsigned)t))
                 : (ull)(0xFFFFFFFFu - (unsigned)t);
    keyL[t] = myk;
    keepS[t] = 0;
    __syncthreads();
    {
        int r = 0;
        for (int k = 0; k < NPROP; k += 8) {
            int acc = 0;
#pragma unroll
            for (int q = 0; q < 8; ++q) acc += (keyL[k+q] > myk) ? 1 : 0;
            r += acc;
        }
        orderL[r] = t;
        if (vi) atomicAdd(&nvalidS, 1);
    }
    for (int k = t; k < NPROP*6; k += NPROP) supL[k] = supG[bc*NPROP*6 + k];
    __syncthreads();
    if (t < 64) {
        int lane = t;
        int NV = nvalidS;
        int ord0 = orderL[lane],      ord1 = orderL[64+lane];
        int ord2 = orderL[128+lane],  ord3 = orderL[192+lane];
        int ord4 = orderL[256+lane],  ord5 = orderL[320+lane];
        ull mask = 0ull;                      // lanes 0..5: 384-bit suppressed set
        int o_cur = __shfl(ord0, 0);
        ull row_cur = (lane < 6) ? supL[o_cur*6 + lane] : 0ull;
        for (int p = 0; p < NV; ++p) {
            int pn = (p + 1 < NPROP) ? (p + 1) : 0;
            int seg = pn >> 6, sl = pn & 63;
            int on = __shfl(ord0, sl);
            on = (seg == 1) ? __shfl(ord1, sl) : on;
            on = (seg == 2) ? __shfl(ord2, sl) : on;
            on = (seg == 3) ? __shfl(ord3, sl) : on;
            on = (seg == 4) ? __shfl(ord4, sl) : on;
            on = (seg == 5) ? __shfl(ord5, sl) : on;
            ull row_next = (lane < 6) ? supL[on*6 + lane] : 0ull;  // prefetch
            bool myhit = (lane == (o_cur >> 6)) && ((mask >> (o_cur & 63)) & 1ull);
            ull bal = __ballot(myhit);
            if (bal == 0ull) {                // keep o_cur
                if (lane == 0) keepS[o_cur] = 1;
                mask |= row_cur;
            }
            row_cur = row_next;
            o_cur = on;
        }
    }
    __syncthreads();
    // compact kept boxes into per-image list (rank formula is order-independent)
    if (keepS[t]) {
        int img = bc / NFG;
        int f = (bc % NFG) * NPROP + t;
        int pos = (int)atomicAdd(&kcntG[img], 1u);
        kidxG[img*FLAT_PER_IMG + pos] = (unsigned)f;
        kscG [img*FLAT_PER_IMG + pos] = sc;
    }
}

// 16 blocks per image; kept list as u64 keys in LDS; unroll-16 rank count.
// key = (score_bits << 32) | (~f): u64 compare == (score desc, f asc).
__global__ __launch_bounds__(256)
void topk_kernel(const float* __restrict__ ws, float* __restrict__ out) {
    __shared__ ull keyL[FLAT_PER_IMG];
    int b = blockIdx.x >> 4;
    int slice = blockIdx.x & 15;
    int t = threadIdx.x;
    const unsigned int* kidxG = (const unsigned int*)(ws + OFF_VIDX);
    const float* kscG = ws + OFF_MS;
    const unsigned int* kcntG = (const unsigned int*)(ws + OFF_VCNT) + 24;
    const float* boxes = ws + OFF_BOXES;
    int K = (int)kcntG[b];
    int KP = (K + 15) & ~15;
    for (int k = t; k < KP; k += 256) {
        ull key = 0ull;
        if (k < K) {
            unsigned sb = __float_as_uint(kscG[b*FLAT_PER_IMG + k]);
            unsigned f  = kidxG[b*FLAT_PER_IMG + k];
            key = ((ull)sb << 32) | (ull)(0xFFFFFFFFu - f);
        }
        keyL[k] = key;
    }
    __syncthreads();
    int e = slice*256 + t;
    if (e >= K) return;
    ull my = keyL[e];
    int r = 0;
    for (int k = 0; k < KP; k += 16) {
        int acc = 0;
#pragma unroll
        for (int q = 0; q < 16; ++q)
            acc += (keyL[k+q] > my) ? 1 : 0;
        r += acc;
    }
    if (r < DET) {
        unsigned f = 0xFFFFFFFFu - (unsigned)(my & 0xFFFFFFFFu);
        float s = __uint_as_float((unsigned)(my >> 32));
        int src = b*FLAT_PER_IMG + (int)f;
        float* row = out + (b*DET + r)*6;
#pragma unroll
        for (int q = 0; q < 5; ++q) row[q] = boxes[src*5+q];
        row[5] = s;
        out[NB*DET*6 + b*DET + r] = (float)(f / NPROP + 1);
    }
}

extern "C" void kernel_launch(void* const* d_in, const int* in_sizes, int n_in,
                              void* d_out, int out_size, void* d_ws, size_t ws_size,
                              hipStream_t stream) {
    const float* logits = (const float*)d_in[0];
    const float* boxreg = (const float*)d_in[1];
    const float* rrects = (const float*)d_in[2];
    float* out = (float*)d_out;
    float* ws  = (float*)d_ws;
    (void)in_sizes; (void)n_in; (void)out_size; (void)ws_size;

    prep_kernel<<<(M_TOTAL + 255) / 256, 256, 0, stream>>>(logits, boxreg, rrects, ws, out);
    compact_kernel<<<BC_TOTAL, NPROP, 0, stream>>>(ws);
    pairgen_kernel<<<(BC_TOTAL * NPROP * 6 * 64) / 256, 256, 0, stream>>>(ws);
    pairheavy_kernel<<<256, 256, 0, stream>>>(ws);
    nms_kernel<<<BC_TOTAL, NPROP, 0, stream>>>(ws);
    topk_kernel<<<NB * 16, 256, 0, stream>>>(ws, out);
}

// Round 8
// 156.216 us; speedup vs baseline: 5.7020x; 1.0248x over previous
//
#include <hip/hip_runtime.h>
#include <cmath>

#define NPROP 384
#define NB 2
#define NCLS 11
#define NFG 10
#define BC_TOTAL (NB*NFG)          // 20
#define M_TOTAL (NB*NPROP)         // 768
#define FLAT_PER_IMG (NFG*NPROP)   // 3840
#define DET 100

// ws layout (in 4-byte words)
#define OFF_BOXES 0                // [BC][N][5]  38400
#define OFF_AREA  38400            // [BC][N]     7680
#define OFF_SCORE 46080            // [BC][N]     7680
#define OFF_VIDX  53760            // kept flat idx [NB][FLAT] (written by nms)
#define OFF_SUP   61440            // [BC][N][12] 92160 (u32 suppress bitrows; 8B-aligned)
#define OFF_MS    153600           // [B][FLAT]   kept scores (compacted)
#define OFF_VCNT  161280           // [24..25] kept counts; [32] pair counter
#define OFF_PAIRS 161344           // pair list, capacity 61440 u32
#define PAIR_CAP  61440

typedef unsigned long long ull;

__device__ __forceinline__ void mk_corners(float px, float py, float pw, float ph, float pa,
                                           float cxo[4], float cyo[4]) {
    float t = pa * 0.017453292519943295f;
    float ct = cosf(t), st = sinf(t);
    float hx = pw*0.5f, hy = ph*0.5f;
    float lx[4] = {-hx, hx, hx, -hx};
    float ly[4] = {-hy, -hy, hy, hy};
#pragma unroll
    for (int k = 0; k < 4; ++k) {
        cxo[k] = px + lx[k]*ct - ly[k]*st;
        cyo[k] = py + lx[k]*st + ly[k]*ct;
    }
}

__device__ float inter_area_net(const float ax[4], const float ay[4],
                                const float bx[4], const float by[4]) {
    float d1x[4], d1y[4], d2x[4], d2y[4];
#pragma unroll
    for (int k = 0; k < 4; ++k) {
        int k1 = (k + 1) & 3;
        d1x[k] = ax[k1] - ax[k]; d1y[k] = ay[k1] - ay[k];
        d2x[k] = bx[k1] - bx[k]; d2y[k] = by[k1] - by[k];
    }
    float ex[32], ey[32];
    bool msk[24];
#pragma unroll
    for (int i = 0; i < 4; ++i) {
#pragma unroll
        for (int j = 0; j < 4; ++j) {
            float den = d1x[i]*d2y[j] - d1y[i]*d2x[j];
            float dfx = bx[j]-ax[i], dfy = by[j]-ay[i];
            float dens = (fabsf(den) < 1e-8f) ? 1.0f : den;
            float t = (dfx*d2y[j] - dfy*d2x[j]) / dens;
            float u = (dfx*d1y[i] - dfy*d1x[i]) / dens;
            bool ok = (fabsf(den) >= 1e-8f) && t >= 0.0f && t <= 1.0f
                                            && u >= 0.0f && u <= 1.0f;
            ex[i*4+j] = ax[i] + t*d1x[i];
            ey[i*4+j] = ay[i] + t*d1y[i];
            msk[i*4+j] = ok;
        }
    }
#pragma unroll
    for (int i = 0; i < 4; ++i) {   // corners of A inside B
        bool allp = true, alln = true;
#pragma unroll
        for (int j = 0; j < 4; ++j) {
            float cr = d2x[j]*(ay[i]-by[j]) - d2y[j]*(ax[i]-bx[j]);
            allp = allp && (cr >= -1e-6f);
            alln = alln && (cr <= 1e-6f);
        }
        ex[16+i] = ax[i]; ey[16+i] = ay[i]; msk[16+i] = allp || alln;
    }
#pragma unroll
    for (int i = 0; i < 4; ++i) {   // corners of B inside A
        bool allp = true, alln = true;
#pragma unroll
        for (int j = 0; j < 4; ++j) {
            float cr = d1x[j]*(by[i]-ay[j]) - d1y[j]*(bx[i]-ax[j]);
            allp = allp && (cr >= -1e-6f);
            alln = alln && (cr <= 1e-6f);
        }
        ex[20+i] = bx[i]; ey[20+i] = by[i]; msk[20+i] = allp || alln;
    }
    int nv = 0; float sx = 0.f, sy = 0.f;
#pragma unroll
    for (int k = 0; k < 24; ++k)
        if (msk[k]) { nv++; sx += ex[k]; sy += ey[k]; }
    float fm = (float)(nv > 1 ? nv : 1);
    float cx = sx / fm, cy = sy / fm;
    unsigned key[32];
#pragma unroll
    for (int k = 0; k < 24; ++k) {
        float qx = msk[k] ? ex[k] : cx;
        float qy = msk[k] ? ey[k] : cy;
        ex[k] = qx; ey[k] = qy;
        float dx = qx - cx, dy = qy - cy;        // parked: dx=dy=+0
        float den = fabsf(dx) + fabsf(dy);
        float r = (den > 0.0f) ? dy / den : 0.0f;
        float p = (dx >= 0.0f) ? r : ((dy >= 0.0f) ? 2.0f - r : -2.0f - r);
        p = p + 0.0f;                             // canonicalize -0 -> +0
        unsigned u = __float_as_uint(p);
        u = (u & 0x80000000u) ? ~u : (u | 0x80000000u);
        key[k] = (u & 0xFFFFFFE0u) | (unsigned)k;
    }
#pragma unroll
    for (int k = 24; k < 32; ++k) { key[k] = 0xFFFFFFFFu; ex[k] = 0.f; ey[k] = 0.f; }
    // bitonic sort, 32 elements ascending, fully unrolled (static idx -> VGPRs)
#pragma unroll
    for (int k = 2; k <= 32; k <<= 1) {
#pragma unroll
        for (int j = k >> 1; j > 0; j >>= 1) {
#pragma unroll
            for (int i = 0; i < 32; ++i) {
                int l = i ^ j;
                if (l > i) {
                    bool up = ((i & k) == 0);
                    unsigned ka = key[i], kb = key[l];
                    bool sw = up ? (ka > kb) : (ka < kb);
                    float xa = ex[i], xb = ex[l];
                    float ya = ey[i], yb = ey[l];
                    key[i] = sw ? kb : ka; key[l] = sw ? ka : kb;
                    ex[i]  = sw ? xb : xa; ex[l]  = sw ? xa : xb;
                    ey[i]  = sw ? yb : ya; ey[l]  = sw ? ya : yb;
                }
            }
        }
    }
    float s = 0.f;
#pragma unroll
    for (int k = 0; k < 24; ++k) {
        int n = (k + 1 == 24) ? 0 : (k + 1);
        s += ex[k]*ey[n] - ey[k]*ex[n];
    }
    float area = 0.5f * fabsf(s);
    return (nv >= 3) ? area : 0.0f;
}

// full pair evaluation: corners from boxes (identical formula everywhere),
// inter_area(c_hi, c_lo), set suppress bit (hi row, lo col) if iou > 0.5
__device__ __forceinline__ void eval_pair(float* ws, int bc, int hi, int lo) {
    const float* boxes = ws + OFF_BOXES;
    const float* areaA = ws + OFF_AREA;
    unsigned int* supw = (unsigned int*)(ws + OFF_SUP);
    int rowi = bc*NPROP + hi, rowj = bc*NPROP + lo;
    float axp[4], ayp[4], bxp[4], byp[4];
    mk_corners(boxes[rowi*5+0], boxes[rowi*5+1], boxes[rowi*5+2],
               boxes[rowi*5+3], boxes[rowi*5+4], axp, ayp);
    mk_corners(boxes[rowj*5+0], boxes[rowj*5+1], boxes[rowj*5+2],
               boxes[rowj*5+3], boxes[rowj*5+4], bxp, byp);
    float inter = inter_area_net(axp, ayp, bxp, byp);
    float iou = inter / (areaA[rowi] + areaA[rowj] - inter + 1e-8f);
    if (iou > 0.5f)
        atomicOr(&supw[rowi*12 + (lo >> 5)], 1u << (lo & 31));
}

// one thread per (proposal, fg-class): full parallel softmax+decode
__global__ __launch_bounds__(256)
void prep_kernel(const float* __restrict__ logits,
                 const float* __restrict__ boxreg,
                 const float* __restrict__ rrects,
                 float* __restrict__ ws,
                 float* __restrict__ out) {
    int q = blockIdx.x * blockDim.x + threadIdx.x;
    if (q < NB*DET*6 + NB*DET) out[q] = 0.0f;    // zero 1400-float output
    unsigned int* vcnt = (unsigned int*)(ws + OFF_VCNT);
    if (q == 0) vcnt[32] = 0u;                   // pair counter
    if (q < NB) vcnt[24 + q] = 0u;               // kept-list counters
    if (q >= M_TOTAL * NFG) return;
    int m  = q / NFG;
    int fg = q % NFG;
    int cls = fg + 1;
    int b = m / NPROP, n = m % NPROP;
    float lg[NCLS];
    float mx = -INFINITY;
#pragma unroll
    for (int c = 0; c < NCLS; ++c) { lg[c] = logits[m*NCLS+c]; mx = fmaxf(mx, lg[c]); }
    float sum = 0.f;
#pragma unroll
    for (int c = 0; c < NCLS; ++c) sum += expf(lg[c]-mx);
    float prob = expf(lg[cls]-mx) / sum;
    float axc = rrects[m*5+0], ayc = rrects[m*5+1];
    float aw  = rrects[m*5+2], ah  = rrects[m*5+3], aa = rrects[m*5+4];
    int o = (b*NFG + fg)*NPROP + n;
    const float* rel = boxreg + m*(NCLS*5) + cls*5;
    float dx = rel[0] / 10.0f;
    float dy = rel[1] / 10.0f;
    float dw = fminf(rel[2] / 5.0f, 4.1351665567423205f);
    float dh = fminf(rel[3] / 5.0f, 4.1351665567423205f);
    float da = rel[4];
    float px = dx*aw + axc;
    float py = dy*ah + ayc;
    float pw = expf(dw)*aw;
    float ph = expf(dh)*ah;
    float pa = da*57.29577951308232f + aa;
    float xm = pa + 180.0f;
    float r = fmodf(xm, 360.0f);
    if (r < 0.0f) r += 360.0f;
    pa = r - 180.0f;
    float* boxes = ws + OFF_BOXES;
    boxes[o*5+0]=px; boxes[o*5+1]=py; boxes[o*5+2]=pw; boxes[o*5+3]=ph; boxes[o*5+4]=pa;
    ws[OFF_AREA + o]  = pw*ph;
    ws[OFF_SCORE + o] = prob;
}

// one block per (b,cls): zero sup rows, compact valid boxes into LDS,
// enumerate all valid pairs from LDS, cull, orient, emit survivors
__global__ __launch_bounds__(384)
void pairgen_kernel(float* __restrict__ ws) {
    __shared__ float cxL[NPROP], cyL[NPROP], radL[NPROP], areaL[NPROP], scoreL[NPROP];
    __shared__ int   origL[NPROP];
    __shared__ int   cntS;
    int bc = blockIdx.x, t = threadIdx.x;
    unsigned int* supw = (unsigned int*)(ws + OFF_SUP);
    unsigned int* pcnt = (unsigned int*)(ws + OFF_VCNT) + 32;
    unsigned int* pairs = (unsigned int*)(ws + OFF_PAIRS);
    const float* boxes = ws + OFF_BOXES;
    int r0 = (bc*NPROP + t)*12;
#pragma unroll
    for (int w = 0; w < 12; ++w) supw[r0 + w] = 0u;
    if (t == 0) cntS = 0;
    __syncthreads();
    int row = bc*NPROP + t;
    float sc = ws[OFF_SCORE + row];
    if (sc > 0.05f) {
        int p = atomicAdd(&cntS, 1);
        float bw = boxes[row*5+2], bh = boxes[row*5+3];
        cxL[p]   = boxes[row*5+0];
        cyL[p]   = boxes[row*5+1];
        radL[p]  = 0.5f*sqrtf(bw*bw + bh*bh);
        areaL[p] = ws[OFF_AREA + row];
        scoreL[p]= sc;
        origL[p] = t;
    }
    __syncthreads();
    int cnt = cntS;
    int wv = t >> 6, lane = t & 63;
    for (int a = wv; a < cnt; a += 6) {
        float cxa = cxL[a], cya = cyL[a], ra = radL[a], Aa = areaL[a], sa = scoreL[a];
        int ia = origL[a];
        for (int b0 = a + 1; b0 < cnt; b0 += 64) {
            int b = b0 + lane;
            bool go = (b < cnt);
            float sb = 0.f; int ib = 0;
            if (go) {
                float ddx = cxa - cxL[b], ddy = cya - cyL[b];
                float rr = ra + radL[b];
                go = (ddx*ddx + ddy*ddy <= rr*rr);
                float Ab = areaL[b];
                float mn = fminf(Aa, Ab);
                go = go && (3.0f*mn > Aa + Ab);      // else iou <= 0.5 provably
                sb = scoreL[b]; ib = origL[b];
            }
            bool afirst = (sa > sb) || (sa == sb && ia < ib);
            int hi = afirst ? ia : ib;
            int lo = afirst ? ib : ia;
            ull m = __ballot(go);
            unsigned base = 0;
            if (lane == 0 && m) base = atomicAdd(pcnt, (unsigned)__popcll(m));
            base = __shfl(base, 0);
            if (go) {
                unsigned pos = base + (unsigned)__popcll(m & ((1ull << lane) - 1ull));
                if (pos < PAIR_CAP)
                    pairs[pos] = ((unsigned)bc << 20) | ((unsigned)hi << 10) | (unsigned)lo;
                else
                    eval_pair(ws, bc, hi, lo);       // overflow fallback
            }
        }
    }
}

// one lane per surviving pair — full 64-lane utilization
__global__ __launch_bounds__(256)
void pairheavy_kernel(float* __restrict__ ws) {
    const unsigned int* pcnt = (const unsigned int*)(ws + OFF_VCNT) + 32;
    const unsigned int* pairs = (const unsigned int*)(ws + OFF_PAIRS);
    unsigned n = *pcnt;
    if (n > PAIR_CAP) n = PAIR_CAP;
    unsigned stride = gridDim.x * blockDim.x;
    for (unsigned p = blockIdx.x * blockDim.x + threadIdx.x; p < n; p += stride) {
        unsigned pk = pairs[p];
        int bc = (int)(pk >> 20);
        int hi = (int)((pk >> 10) & 0x3FF);
        int lo = (int)(pk & 0x3FF);
        eval_pair(ws, bc, hi, lo);
    }
}

// wave-parallel greedy NMS: suppressed set in wave-0 registers (lanes 0..5),
// row/order fetches prefetched out of the decision chain.
__global__ __launch_bounds__(384)
void nms_kernel(float* __restrict__ ws) {
    __shared__ ull keyL[NPROP];            // 3 KB
    __shared__ int orderL[NPROP];
    __shared__ ull supL[NPROP*6];          // 18.4 KB (u64 rows, original-index space)
    __shared__ unsigned char keepS[NPROP];
    __shared__ int nvalidS;
    int bc = blockIdx.x, t = threadIdx.x;
    const float* scoreA = ws + OFF_SCORE;
    const ull* supG = (const ull*)((const unsigned int*)(ws + OFF_SUP));
    unsigned int* kidxG = (unsigned int*)(ws + OFF_VIDX);   // kept flat idx [NB][FLAT]
    float* kscG = ws + OFF_MS;                              // kept scores [NB][FLAT]
    unsigned int* kcntG = (unsigned int*)(ws + OFF_VCNT) + 24;
    if (t == 0) nvalidS = 0;
    float sc = scoreA[bc*NPROP + t];
    bool vi = sc > 0.05f;
    ull myk = vi ? (((ull)__float_as_uint(sc) << 32) | (ull)(0xFFFFFFFFu - (unsigned)t))
                 : (ull)(0xFFFFFFFFu - (unsigned)t);
    keyL[t] = myk;
    keepS[t] = 0;
    __syncthreads();
    {
        int r = 0;
        for (int k = 0; k < NPROP; k += 8) {
            int acc = 0;
#pragma unroll
            for (int q = 0; q < 8; ++q) acc += (keyL[k+q] > myk) ? 1 : 0;
            r += acc;
        }
        orderL[r] = t;
        if (vi) atomicAdd(&nvalidS, 1);
    }
    for (int k = t; k < NPROP*6; k += NPROP) supL[k] = supG[bc*NPROP*6 + k];
    __syncthreads();
    if (t < 64) {
        int lane = t;
        int NV = nvalidS;
        int ord0 = orderL[lane],      ord1 = orderL[64+lane];
        int ord2 = orderL[128+lane],  ord3 = orderL[192+lane];
        int ord4 = orderL[256+lane],  ord5 = orderL[320+lane];
        ull mask = 0ull;                      // lanes 0..5: 384-bit suppressed set
        int o_cur = __shfl(ord0, 0);
        ull row_cur = (lane < 6) ? supL[o_cur*6 + lane] : 0ull;
        for (int p = 0; p < NV; ++p) {
            int pn = (p + 1 < NPROP) ? (p + 1) : 0;
            int seg = pn >> 6, sl = pn & 63;
            int on = __shfl(ord0, sl);
            on = (seg == 1) ? __shfl(ord1, sl) : on;
            on = (seg == 2) ? __shfl(ord2, sl) : on;
            on = (seg == 3) ? __shfl(ord3, sl) : on;
            on = (seg == 4) ? __shfl(ord4, sl) : on;
            on = (seg == 5) ? __shfl(ord5, sl) : on;
            ull row_next = (lane < 6) ? supL[on*6 + lane] : 0ull;  // prefetch
            bool myhit = (lane == (o_cur >> 6)) && ((mask >> (o_cur & 63)) & 1ull);
            ull bal = __ballot(myhit);
            if (bal == 0ull) {                // keep o_cur
                if (lane == 0) keepS[o_cur] = 1;
                mask |= row_cur;
            }
            row_cur = row_next;
            o_cur = on;
        }
    }
    __syncthreads();
    // compact kept boxes into per-image list (rank formula is order-independent)
    if (keepS[t]) {
        int img = bc / NFG;
        int f = (bc % NFG) * NPROP + t;
        int pos = (int)atomicAdd(&kcntG[img], 1u);
        kidxG[img*FLAT_PER_IMG + pos] = (unsigned)f;
        kscG [img*FLAT_PER_IMG + pos] = sc;
    }
}

// 16 blocks per image; kept list as u64 keys in LDS; unroll-16 rank count.
// key = (score_bits << 32) | (~f): u64 compare == (score desc, f asc).
__global__ __launch_bounds__(256)
void topk_kernel(const float* __restrict__ ws, float* __restrict__ out) {
    __shared__ ull keyL[FLAT_PER_IMG];
    int b = blockIdx.x >> 4;
    int slice = blockIdx.x & 15;
    int t = threadIdx.x;
    const unsigned int* kidxG = (const unsigned int*)(ws + OFF_VIDX);
    const float* kscG = ws + OFF_MS;
    const unsigned int* kcntG = (const unsigned int*)(ws + OFF_VCNT) + 24;
    const float* boxes = ws + OFF_BOXES;
    int K = (int)kcntG[b];
    int KP = (K + 15) & ~15;
    for (int k = t; k < KP; k += 256) {
        ull key = 0ull;
        if (k < K) {
            unsigned sb = __float_as_uint(kscG[b*FLAT_PER_IMG + k]);
            unsigned f  = kidxG[b*FLAT_PER_IMG + k];
            key = ((ull)sb << 32) | (ull)(0xFFFFFFFFu - f);
        }
        keyL[k] = key;
    }
    __syncthreads();
    int e = slice*256 + t;
    if (e >= K) return;
    ull my = keyL[e];
    int r = 0;
    for (int k = 0; k < KP; k += 16) {
        int acc = 0;
#pragma unroll
        for (int q = 0; q < 16; ++q)
            acc += (keyL[k+q] > my) ? 1 : 0;
        r += acc;
    }
    if (r < DET) {
        unsigned f = 0xFFFFFFFFu - (unsigned)(my & 0xFFFFFFFFu);
        float s = __uint_as_float((unsigned)(my >> 32));
        int src = b*FLAT_PER_IMG + (int)f;
        float* row = out + (b*DET + r)*6;
#pragma unroll
        for (int q = 0; q < 5; ++q) row[q] = boxes[src*5+q];
        row[5] = s;
        out[NB*DET*6 + b*DET + r] = (float)(f / NPROP + 1);
    }
}

extern "C" void kernel_launch(void* const* d_in, const int* in_sizes, int n_in,
                              void* d_out, int out_size, void* d_ws, size_t ws_size,
                              hipStream_t stream) {
    const float* logits = (const float*)d_in[0];
    const float* boxreg = (const float*)d_in[1];
    const float* rrects = (const float*)d_in[2];
    float* out = (float*)d_out;
    float* ws  = (float*)d_ws;
    (void)in_sizes; (void)n_in; (void)out_size; (void)ws_size;

    prep_kernel<<<(M_TOTAL*NFG + 255) / 256, 256, 0, stream>>>(logits, boxreg, rrects, ws, out);
    pairgen_kernel<<<BC_TOTAL, NPROP, 0, stream>>>(ws);
    pairheavy_kernel<<<256, 256, 0, stream>>>(ws);
    nms_kernel<<<BC_TOTAL, NPROP, 0, stream>>>(ws);
    topk_kernel<<<NB * 16, 256, 0, stream>>>(ws, out);
}

// Round 9
// 142.772 us; speedup vs baseline: 6.2389x; 1.0942x over previous
//
#include <hip/hip_runtime.h>
#include <cmath>

#define NPROP 384
#define NB 2
#define NCLS 11
#define NFG 10
#define BC_TOTAL (NB*NFG)          // 20
#define M_TOTAL (NB*NPROP)         // 768
#define FLAT_PER_IMG (NFG*NPROP)   // 3840
#define DET 100
#define PAIR_LDS_CAP 6144

// ws layout (in 4-byte words)
#define OFF_BOXES 0                // [BC][N][5]  38400
#define OFF_KIDX  38400            // [BC][N] u32 kept flat-in-image idx (per-bc slices)
#define OFF_KSC   46080            // [BC][N] kept scores (per-bc slices)
#define OFF_KCNT  53760            // [BC] u32 kept counts

typedef unsigned long long ull;

__device__ __forceinline__ void mk_corners(float px, float py, float pw, float ph, float pa,
                                           float cxo[4], float cyo[4]) {
    float t = pa * 0.017453292519943295f;
    float ct = cosf(t), st = sinf(t);
    float hx = pw*0.5f, hy = ph*0.5f;
    float lx[4] = {-hx, hx, hx, -hx};
    float ly[4] = {-hy, -hy, hy, hy};
#pragma unroll
    for (int k = 0; k < 4; ++k) {
        cxo[k] = px + lx[k]*ct - ly[k]*st;
        cyo[k] = py + lx[k]*st + ly[k]*ct;
    }
}

// Register-only quirk-faithful intersection area (park-at-centroid + sort-all-24
// + shoelace). Bitonic-32 network keeps everything in VGPRs.
__device__ float inter_area_net(const float ax[4], const float ay[4],
                                const float bx[4], const float by[4]) {
    float d1x[4], d1y[4], d2x[4], d2y[4];
#pragma unroll
    for (int k = 0; k < 4; ++k) {
        int k1 = (k + 1) & 3;
        d1x[k] = ax[k1] - ax[k]; d1y[k] = ay[k1] - ay[k];
        d2x[k] = bx[k1] - bx[k]; d2y[k] = by[k1] - by[k];
    }
    float ex[32], ey[32];
    bool msk[24];
#pragma unroll
    for (int i = 0; i < 4; ++i) {
#pragma unroll
        for (int j = 0; j < 4; ++j) {
            float den = d1x[i]*d2y[j] - d1y[i]*d2x[j];
            float dfx = bx[j]-ax[i], dfy = by[j]-ay[i];
            float dens = (fabsf(den) < 1e-8f) ? 1.0f : den;
            float t = (dfx*d2y[j] - dfy*d2x[j]) / dens;
            float u = (dfx*d1y[i] - dfy*d1x[i]) / dens;
            bool ok = (fabsf(den) >= 1e-8f) && t >= 0.0f && t <= 1.0f
                                            && u >= 0.0f && u <= 1.0f;
            ex[i*4+j] = ax[i] + t*d1x[i];
            ey[i*4+j] = ay[i] + t*d1y[i];
            msk[i*4+j] = ok;
        }
    }
#pragma unroll
    for (int i = 0; i < 4; ++i) {   // corners of A inside B
        bool allp = true, alln = true;
#pragma unroll
        for (int j = 0; j < 4; ++j) {
            float cr = d2x[j]*(ay[i]-by[j]) - d2y[j]*(ax[i]-bx[j]);
            allp = allp && (cr >= -1e-6f);
            alln = alln && (cr <= 1e-6f);
        }
        ex[16+i] = ax[i]; ey[16+i] = ay[i]; msk[16+i] = allp || alln;
    }
#pragma unroll
    for (int i = 0; i < 4; ++i) {   // corners of B inside A
        bool allp = true, alln = true;
#pragma unroll
        for (int j = 0; j < 4; ++j) {
            float cr = d1x[j]*(by[i]-ay[j]) - d1y[j]*(bx[i]-ax[j]);
            allp = allp && (cr >= -1e-6f);
            alln = alln && (cr <= 1e-6f);
        }
        ex[20+i] = bx[i]; ey[20+i] = by[i]; msk[20+i] = allp || alln;
    }
    int nv = 0; float sx = 0.f, sy = 0.f;
#pragma unroll
    for (int k = 0; k < 24; ++k)
        if (msk[k]) { nv++; sx += ex[k]; sy += ey[k]; }
    float fm = (float)(nv > 1 ? nv : 1);
    float cx = sx / fm, cy = sy / fm;
    unsigned key[32];
#pragma unroll
    for (int k = 0; k < 24; ++k) {
        float qx = msk[k] ? ex[k] : cx;
        float qy = msk[k] ? ey[k] : cy;
        ex[k] = qx; ey[k] = qy;
        float dx = qx - cx, dy = qy - cy;        // parked: dx=dy=+0
        float den = fabsf(dx) + fabsf(dy);
        float r = (den > 0.0f) ? dy / den : 0.0f;
        float p = (dx >= 0.0f) ? r : ((dy >= 0.0f) ? 2.0f - r : -2.0f - r);
        p = p + 0.0f;                             // canonicalize -0 -> +0
        unsigned u = __float_as_uint(p);
        u = (u & 0x80000000u) ? ~u : (u | 0x80000000u);
        key[k] = (u & 0xFFFFFFE0u) | (unsigned)k;
    }
#pragma unroll
    for (int k = 24; k < 32; ++k) { key[k] = 0xFFFFFFFFu; ex[k] = 0.f; ey[k] = 0.f; }
#pragma unroll
    for (int k = 2; k <= 32; k <<= 1) {
#pragma unroll
        for (int j = k >> 1; j > 0; j >>= 1) {
#pragma unroll
            for (int i = 0; i < 32; ++i) {
                int l = i ^ j;
                if (l > i) {
                    bool up = ((i & k) == 0);
                    unsigned ka = key[i], kb = key[l];
                    bool sw = up ? (ka > kb) : (ka < kb);
                    float xa = ex[i], xb = ex[l];
                    float ya = ey[i], yb = ey[l];
                    key[i] = sw ? kb : ka; key[l] = sw ? ka : kb;
                    ex[i]  = sw ? xb : xa; ex[l]  = sw ? xa : xb;
                    ey[i]  = sw ? yb : ya; ey[l]  = sw ? ya : yb;
                }
            }
        }
    }
    float s = 0.f;
#pragma unroll
    for (int k = 0; k < 24; ++k) {
        int n = (k + 1 == 24) ? 0 : (k + 1);
        s += ex[k]*ey[n] - ey[k]*ex[n];
    }
    float area = 0.5f * fabsf(s);
    return (nv >= 3) ? area : 0.0f;
}

// evaluate one pair entirely from LDS box data; set suppress bit via LDS atomicOr
__device__ __forceinline__ void eval_pair_lds(const float* pxL, const float* pyL,
                                              const float* pwL, const float* phL,
                                              const float* paL, const float* areaL,
                                              ull* supL, int hi, int lo) {
    float axp[4], ayp[4], bxp[4], byp[4];
    mk_corners(pxL[hi], pyL[hi], pwL[hi], phL[hi], paL[hi], axp, ayp);
    mk_corners(pxL[lo], pyL[lo], pwL[lo], phL[lo], paL[lo], bxp, byp);
    float inter = inter_area_net(axp, ayp, bxp, byp);
    float iou = inter / (areaL[hi] + areaL[lo] - inter + 1e-8f);
    if (iou > 0.5f)
        atomicOr((unsigned int*)supL + hi*12 + (lo >> 5), 1u << (lo & 31));
}

// ONE block per (b,cls): decode -> valid compact -> pair enum (LDS) ->
// heavy eval (LDS supmatrix) -> wave-parallel NMS walk -> kept append
__global__ __launch_bounds__(384)
void bc_kernel(const float* __restrict__ logits,
               const float* __restrict__ boxreg,
               const float* __restrict__ rrects,
               float* __restrict__ ws,
               float* __restrict__ out) {
    __shared__ float pxL[NPROP], pyL[NPROP], pwL[NPROP], phL[NPROP], paL[NPROP];
    __shared__ float areaL[NPROP], scoreL[NPROP], radL[NPROP];
    __shared__ int   origL[NPROP];
    __shared__ ull   supL[NPROP*6];          // 18.4 KB, original-index space
    __shared__ unsigned pairL[PAIR_LDS_CAP]; // 24 KB
    __shared__ ull   keyL[NPROP];
    __shared__ int   orderL[NPROP];
    __shared__ unsigned char keepS[NPROP];
    __shared__ int   wcntS[8];
    __shared__ int   cntS, pcntS;

    int bc = blockIdx.x, t = threadIdx.x;
    int b = bc / NFG, cls = (bc % NFG) + 1;
    int wv = t >> 6, lane = t & 63;

    // ---- phase 0: decode + LDS/global staging ----
    int gq = bc*NPROP + t;
    if (gq < NB*DET*6 + NB*DET) out[gq] = 0.0f;   // zero 1400-float output
    if (t == 0) { cntS = 0; pcntS = 0; }
    keepS[t] = 0;
    for (int k = t; k < NPROP*6; k += NPROP) supL[k] = 0ull;
    {
        int m = b*NPROP + t;
        float lg[NCLS];
        float mx = -INFINITY;
#pragma unroll
        for (int c = 0; c < NCLS; ++c) { lg[c] = logits[m*NCLS+c]; mx = fmaxf(mx, lg[c]); }
        float sum = 0.f;
#pragma unroll
        for (int c = 0; c < NCLS; ++c) sum += expf(lg[c]-mx);
        float prob = expf(lg[cls]-mx) / sum;
        float axc = rrects[m*5+0], ayc = rrects[m*5+1];
        float aw  = rrects[m*5+2], ah  = rrects[m*5+3], aa = rrects[m*5+4];
        const float* rel = boxreg + m*(NCLS*5) + cls*5;
        float dx = rel[0] / 10.0f;
        float dy = rel[1] / 10.0f;
        float dw = fminf(rel[2] / 5.0f, 4.1351665567423205f);
        float dh = fminf(rel[3] / 5.0f, 4.1351665567423205f);
        float da = rel[4];
        float px = dx*aw + axc;
        float py = dy*ah + ayc;
        float pw = expf(dw)*aw;
        float ph = expf(dh)*ah;
        float pa = da*57.29577951308232f + aa;
        float xm = pa + 180.0f;
        float r = fmodf(xm, 360.0f);
        if (r < 0.0f) r += 360.0f;
        pa = r - 180.0f;
        pxL[t]=px; pyL[t]=py; pwL[t]=pw; phL[t]=ph; paL[t]=pa;
        areaL[t]=pw*ph; scoreL[t]=prob;
        radL[t]=0.5f*sqrtf(pw*pw + ph*ph);
        float* boxes = ws + OFF_BOXES;
        int o = bc*NPROP + t;
        boxes[o*5+0]=px; boxes[o*5+1]=py; boxes[o*5+2]=pw; boxes[o*5+3]=ph; boxes[o*5+4]=pa;
        bool vi = prob > 0.05f;
        keyL[t] = vi ? (((ull)__float_as_uint(prob) << 32) | (ull)(0xFFFFFFFFu - (unsigned)t))
                     : (ull)(0xFFFFFFFFu - (unsigned)t);
    }
    __syncthreads();

    // ---- phase 1: valid compaction + rank-sort (u64 keys) ----
    if (scoreL[t] > 0.05f) {
        int p = atomicAdd(&cntS, 1);
        origL[p] = t;
    }
    {
        ull myk = keyL[t];
        int r = 0;
        for (int k = 0; k < NPROP; k += 8) {
            int acc = 0;
#pragma unroll
            for (int q = 0; q < 8; ++q) acc += (keyL[k+q] > myk) ? 1 : 0;
            r += acc;
        }
        orderL[r] = t;
    }
    __syncthreads();
    int cnt = cntS;

    // ---- phase 2: pair enumeration from LDS (culls + orient), LDS pair list ----
    for (int a = wv; a < cnt; a += 6) {
        int ia = origL[a];
        float cxa = pxL[ia], cya = pyL[ia], ra = radL[ia], Aa = areaL[ia], sa = scoreL[ia];
        for (int b0 = a + 1; b0 < cnt; b0 += 64) {
            int bb = b0 + lane;
            bool go = false; int ib = 0;
            if (bb < cnt) {
                ib = origL[bb];
                float ddx = cxa - pxL[ib], ddy = cya - pyL[ib];
                float rr = ra + radL[ib];
                go = (ddx*ddx + ddy*ddy <= rr*rr);
                float Ab = areaL[ib];
                float mn = fminf(Aa, Ab);
                go = go && (3.0f*mn > Aa + Ab);      // else iou <= 0.5 provably
            }
            if (go) {
                float sb = scoreL[ib];
                bool afirst = (sa > sb) || (sa == sb && ia < ib);
                int hi = afirst ? ia : ib;
                int lo = afirst ? ib : ia;
                int pos = atomicAdd(&pcntS, 1);
                if (pos < PAIR_LDS_CAP)
                    pairL[pos] = ((unsigned)hi << 16) | (unsigned)lo;
                else
                    eval_pair_lds(pxL, pyL, pwL, phL, paL, areaL, supL, hi, lo);
            }
        }
    }
    __syncthreads();

    // ---- phase 3: dense heavy eval over the block's pair list ----
    {
        int np = pcntS; if (np > PAIR_LDS_CAP) np = PAIR_LDS_CAP;
        for (int p = t; p < np; p += NPROP) {
            unsigned pk = pairL[p];
            eval_pair_lds(pxL, pyL, pwL, phL, paL, areaL, supL,
                          (int)(pk >> 16), (int)(pk & 0xFFFFu));
        }
    }
    __syncthreads();

    // ---- phase 4: wave-parallel greedy NMS walk (wave 0) ----
    if (t < 64) {
        int NV = cnt;
        int ord0 = orderL[lane],      ord1 = orderL[64+lane];
        int ord2 = orderL[128+lane],  ord3 = orderL[192+lane];
        int ord4 = orderL[256+lane],  ord5 = orderL[320+lane];
        ull mask = 0ull;                      // lanes 0..5: 384-bit suppressed set
        int o_cur = __shfl(ord0, 0);
        ull row_cur = (lane < 6) ? supL[o_cur*6 + lane] : 0ull;
        for (int p = 0; p < NV; ++p) {
            int pn = (p + 1 < NPROP) ? (p + 1) : 0;
            int seg = pn >> 6, sl = pn & 63;
            int on = __shfl(ord0, sl);
            on = (seg == 1) ? __shfl(ord1, sl) : on;
            on = (seg == 2) ? __shfl(ord2, sl) : on;
            on = (seg == 3) ? __shfl(ord3, sl) : on;
            on = (seg == 4) ? __shfl(ord4, sl) : on;
            on = (seg == 5) ? __shfl(ord5, sl) : on;
            ull row_next = (lane < 6) ? supL[on*6 + lane] : 0ull;  // prefetch
            bool myhit = (lane == (o_cur >> 6)) && ((mask >> (o_cur & 63)) & 1ull);
            ull bal = __ballot(myhit);
            if (bal == 0ull) {                // keep o_cur
                if (lane == 0) keepS[o_cur] = 1;
                mask |= row_cur;
            }
            row_cur = row_next;
            o_cur = on;
        }
    }
    __syncthreads();

    // ---- phase 5: kept append into this bc's own slice (no cross-block atomics) ----
    bool kp = keepS[t] != 0;
    ull bal = __ballot(kp);
    if (lane == 0) wcntS[wv] = __popcll(bal);
    __syncthreads();
    if (t == 0) {
        int s = 0;
#pragma unroll
        for (int w = 0; w < 6; ++w) { int c = wcntS[w]; wcntS[w] = s; s += c; }
        ((unsigned int*)(ws + OFF_KCNT))[bc] = (unsigned)s;
    }
    __syncthreads();
    if (kp) {
        int pos = wcntS[wv] + (int)__popcll(bal & ((1ull << lane) - 1ull));
        ((unsigned int*)(ws + OFF_KIDX))[bc*NPROP + pos] = (unsigned)((bc % NFG)*NPROP + t);
        (ws + OFF_KSC)[bc*NPROP + pos] = scoreL[t];
    }
}

// 16 blocks per image; concatenate the image's 10 kept slices as u64 keys in
// LDS (order-independent rank), unroll-16 rank count, write top-100 rows.
__global__ __launch_bounds__(256)
void topk_kernel(const float* __restrict__ ws, float* __restrict__ out) {
    __shared__ ull keyL[FLAT_PER_IMG];
    int b = blockIdx.x >> 4;
    int slice = blockIdx.x & 15;
    int t = threadIdx.x;
    const unsigned int* kidx2 = (const unsigned int*)(ws + OFF_KIDX);
    const float* ksc2 = ws + OFF_KSC;
    const unsigned int* kcnt2 = (const unsigned int*)(ws + OFF_KCNT);
    const float* boxes = ws + OFF_BOXES;
    int offs[NFG], cnts[NFG];
    int K = 0;
#pragma unroll
    for (int fg = 0; fg < NFG; ++fg) {
        cnts[fg] = (int)kcnt2[b*NFG + fg];
        offs[fg] = K;
        K += cnts[fg];
    }
#pragma unroll
    for (int fg = 0; fg < NFG; ++fg) {
        int bc = b*NFG + fg;
        for (int k = t; k < cnts[fg]; k += 256) {
            unsigned sb = __float_as_uint(ksc2[bc*NPROP + k]);
            unsigned f  = kidx2[bc*NPROP + k];
            keyL[offs[fg] + k] = ((ull)sb << 32) | (ull)(0xFFFFFFFFu - f);
        }
    }
    int KP = (K + 15) & ~15;
    for (int k = K + t; k < KP; k += 256) keyL[k] = 0ull;
    __syncthreads();
    int e = slice*256 + t;
    if (e >= K) return;
    ull my = keyL[e];
    int r = 0;
    for (int k = 0; k < KP; k += 16) {
        int acc = 0;
#pragma unroll
        for (int q = 0; q < 16; ++q)
            acc += (keyL[k+q] > my) ? 1 : 0;
        r += acc;
    }
    if (r < DET) {
        unsigned f = 0xFFFFFFFFu - (unsigned)(my & 0xFFFFFFFFu);
        float s = __uint_as_float((unsigned)(my >> 32));
        int src = b*FLAT_PER_IMG + (int)f;
        float* row = out + (b*DET + r)*6;
#pragma unroll
        for (int q = 0; q < 5; ++q) row[q] = boxes[src*5+q];
        row[5] = s;
        out[NB*DET*6 + b*DET + r] = (float)(f / NPROP + 1);
    }
}

extern "C" void kernel_launch(void* const* d_in, const int* in_sizes, int n_in,
                              void* d_out, int out_size, void* d_ws, size_t ws_size,
                              hipStream_t stream) {
    const float* logits = (const float*)d_in[0];
    const float* boxreg = (const float*)d_in[1];
    const float* rrects = (const float*)d_in[2];
    float* out = (float*)d_out;
    float* ws  = (float*)d_ws;
    (void)in_sizes; (void)n_in; (void)out_size; (void)ws_size;

    bc_kernel<<<BC_TOTAL, NPROP, 0, stream>>>(logits, boxreg, rrects, ws, out);
    topk_kernel<<<NB * 16, 256, 0, stream>>>(ws, out);
}